// Round 2
// baseline (1594.438 us; speedup 1.0000x reference)
//
#include <hip/hip_runtime.h>
#include <hip/hip_bf16.h>

// B=32, T=2048, D=256, H=256, CS=32, N=8, G=4H+2N=1040.
// Scan over BATCH axis (32 steps), carry (T,H). Backward dir = col-reversed W_ih.
#define B_  32
#define T_  2048
#define D_  256
#define H_  256
#define G_  1040

#define NSL 8      // e-slices of width 32 (== CS; slice s == chunk n)
#define NRB 16     // row-blocks of 128 rows
#define NMB 4      // mblocks (1 per wave) of 32 rows
#define NKB 32     // K16 chunks over KK=512
#define NF  5      // B col-frags: og,cg,ig,fg (32 cols) + [cols 0..15 | zeros]

using bf16   = __hip_bfloat16;
using short8 = __attribute__((ext_vector_type(8))) short;
using f32x16 = __attribute__((ext_vector_type(16))) float;

__device__ inline float sigmoidf_(float v) { return 1.f / (1.f + __expf(-v)); }
__device__ inline float tanh_(float v) {
  v = fminf(fmaxf(v, -15.f), 15.f);
  float e = __expf(2.f * v);
  return (e - 1.f) / (e + 1.f);
}
__device__ inline float bf2f(unsigned short u) {
  union { unsigned int i; float f; } c; c.i = ((unsigned int)u) << 16; return c.f;
}
__device__ inline float ldF(const void* p, size_t i, int isf) {
  return isf ? ((const float*)p)[i] : bf2f(((const unsigned short*)p)[i]);
}
__device__ inline short f2bs(float v) {
  bf16 h = __float2bfloat16(v);
  return *(short*)&h;
}

// meta: [0]=is_fp32, [8+b]=seq_len[b], [40+b]=row base[b]
__global__ __launch_bounds__(256) void detect_prep(
    const unsigned short* __restrict__ xh, const int* __restrict__ sli,
    int* __restrict__ meta)
{
  __shared__ int s_bad;
  if (threadIdx.x == 0) s_bad = 0;
  __syncthreads();
  int bad = 0;
  for (int i = threadIdx.x; i < 1024; i += 256) {
    float f = bf2f(xh[i]);
    if (!(fabsf(f) < 100.f)) bad = 1;
  }
  if (bad) atomicOr(&s_bad, 1);
  __syncthreads();
  if (threadIdx.x == 0) {
    meta[0] = s_bad;
    bool is64 = true;
    for (int i = 1; i < 32; i += 2) if (sli[i] != 0) is64 = false;
    int base = 0;
    for (int b = 0; b < B_; ++b) {
      int v = is64 ? sli[2 * b] : sli[b];
      meta[8 + b]  = v;
      meta[40 + b] = base;
      base += v;
    }
  }
}

__global__ __launch_bounds__(256) void build_bsum(
    const void* __restrict__ b_ih, const void* __restrict__ b_hh,
    float* __restrict__ bsum, const int* __restrict__ meta)
{
  const int isf = meta[0];
  int i = blockIdx.x * 256 + threadIdx.x;
  if (i < G_) bsum[i] = ldF(b_ih, i, isf) + ldF(b_hh, i, isf);
}

// xs[b][rb(16)][kbx(16)][mb(4)][lane(64)][8]: A-frag image for 32x32x16
__global__ __launch_bounds__(256) void build_xs(
    const void* __restrict__ x, bf16* __restrict__ xs,
    const int* __restrict__ meta)
{
  const int isf = meta[0];
  size_t idx = (size_t)blockIdx.x * 256 + threadIdx.x;   // over B*T*D/8
  if (idx >= (size_t)B_ * T_ * D_ / 8) return;
  const int lane = idx & 63;
  const int mb   = (idx >> 6) & 3;
  const int kbx  = (idx >> 8) & 15;
  const int rb   = (idx >> 12) & 15;
  const int b    = idx >> 16;
  const int t  = rb * 128 + mb * 32 + (lane & 31);
  const int k0 = kbx * 16 + (lane >> 5) * 8;
  const size_t src = ((size_t)b * T_ + t) * D_ + k0;
  short8 v;
  #pragma unroll
  for (int j = 0; j < 8; ++j) v[j] = f2bs(ldF(x, src + j, isf));
  *(short8*)(xs + idx * 8) = v;
}

// Wsw[d][s][kb(32)][f(5)][lane(64)][8]: B-frag image for 32x32x16
__global__ __launch_bounds__(256) void build_wsw(
    const void* __restrict__ W_ih, const void* __restrict__ W_hh,
    bf16* __restrict__ Wsw, const int* __restrict__ meta)
{
  const int isf = meta[0];
  int idx = blockIdx.x * 256 + threadIdx.x;   // over 2*8*32*5*64 = 163840
  if (idx >= 2 * NSL * NKB * NF * 64) return;
  const int lane = idx & 63;
  const int f    = (idx >> 6) % NF;
  const int kb   = (idx / (64 * NF)) % NKB;
  const int sl   = (idx / (64 * NF * NKB)) % NSL;
  const int d    = idx / (64 * NF * NKB * NSL);
  const int n    = lane & 31;
  const int k0   = kb * 16 + (lane >> 5) * 8;
  const int g = (f < 4) ? (16 + f * H_ + sl * 32 + n) : ((n < 16) ? n : -1);
  short8 v;
  #pragma unroll
  for (int j = 0; j < 8; ++j) {
    float val = 0.f;
    const int k = k0 + j;
    if (g >= 0)
      val = (k < D_) ? ldF(W_ih, (size_t)g * D_ + (d ? (D_ - 1 - k) : k), isf)
                     : ldF(W_hh, (size_t)g * H_ + (k - D_), isf);
    v[j] = f2bs(val);
  }
  *(short8*)(Wsw + (size_t)idx * 8) = v;
}

// ---------------------------------------------------------------------------
// Persistent fused recurrence (see round-1 comments). New this round:
//  - (b_lo, b_hi) parameterization: persistent cooperative launch runs (0,32);
//    fallback runs 32 per-step launches where inter-step sync = kernel
//    boundary (spins satisfy immediately; c carry spills to cs).
//  - spin TIMEOUT (s_memrealtime ~0.4s): a residency/coherence surprise now
//    fails verification gracefully instead of hanging the GPU queue.
// ---------------------------------------------------------------------------
__global__ __launch_bounds__(256, 1) void onlstm_persist(
    const short* __restrict__ xs, const short* __restrict__ Wsw,
    short* __restrict__ hs, float* __restrict__ cs,
    const float* __restrict__ bsum, void* __restrict__ out,
    const int* __restrict__ meta, int* __restrict__ ctr,
    int b_lo, int b_hi)
{
  __shared__ short Wl[NKB * 4 * 512];   // 128 KiB: frags f0..3, all 32 K-chunks

  const int tid  = threadIdx.x;
  const int lane = tid & 63;
  const int w    = tid >> 6;            // wave = mblock

  // XCD-grouped: group (rb,d) siblings (s=0..7) share lin%8 -> same XCD.
  const int lin = blockIdx.x;
  const int rb  = (lin & 7) + 8 * ((lin >> 3) >> 4);
  const int p   = (lin >> 3) & 15;
  const int d   = p >> 3;
  const int s   = p & 7;

  const int col   = lane & 31;
  const int khalf = lane >> 5;
  const int isf   = meta[0];

  const short* wsrc = Wsw + ((size_t)(d * NSL + s) * NKB) * (NF * 512);

  // ---- one-time: stage f0..3 frags into LDS (coalesced 16B/lane) ----
  for (int i = tid; i < NKB * 4 * 64; i += 256) {
    const int kb = i >> 8, rem = i & 255, f = rem >> 6, l = rem & 63;
    *(short8*)&Wl[((kb * 4 + f) << 9) + (l << 3)] =
        *(const short8*)(wsrc + ((kb * 5 + f) << 9) + (l << 3));
  }
  __syncthreads();

  // bias preloads (L1/L2 hits)
  float bg[4];
  #pragma unroll
  for (int f = 0; f < 4; ++f) bg[f] = bsum[16 + f * H_ + s * 32 + col];
  const float c0b = (col < 16) ? bsum[col] : 0.f;

  // epilogue addressing for e = s*32+col
  const int e   = s * 32 + col;
  const int k8e = (e >> 3) & 1, ele = e & 7, kbh = e >> 4;

  int* gctr = ctr + (d * NRB + rb);               // 8-block group (rb,d)
  const short* w4p = wsrc + 4 * 512 + lane * 8;   // f4 frag, stride 5*512/chunk

  float* csP = cs + (((size_t)(d * NSL + s) * NRB + rb) * NMB + w) * 1024 + lane;

  f32x16 creg;                                    // c carry: registers
  if (b_lo > 0) {
    #pragma unroll
    for (int r = 0; r < 16; ++r) creg[r] = csP[r * 64];
  } else {
    #pragma unroll
    for (int r = 0; r < 16; ++r) creg[r] = 0.f;
  }

  for (int b = b_lo; b < b_hi; ++b) {
    const int len_s  = meta[8 + b];
    const int base_s = meta[40 + b];

    f32x16 acc[NF];
    #pragma unroll
    for (int f = 0; f < NF; ++f)
      #pragma unroll
      for (int r = 0; r < 16; ++r) acc[f][r] = 0.f;

    // barrier-free GEMM half: 16 chunks, A + f4 pipelined 3 deep from global,
    // f0..3 from LDS-resident W.
    auto gemm_half = [&](const short* aPtr, const short* w4q, const int kbase) {
      short8 a0 = *(const short8*)(aPtr);
      short8 a1 = *(const short8*)(aPtr + 2048);
      short8 a2 = *(const short8*)(aPtr + 4096);
      short8 q0 = *(const short8*)(w4q);
      short8 q1 = *(const short8*)(w4q + 2560);
      short8 q2 = *(const short8*)(w4q + 5120);
      #pragma unroll
      for (int kb = 0; kb < 16; ++kb) {
        const short8 af = a0, b4 = q0;
        a0 = a1; a1 = a2; q0 = q1; q1 = q2;
        if (kb < 13) {
          a2 = *(const short8*)(aPtr + (kb + 3) * 2048);
          q2 = *(const short8*)(w4q + (kb + 3) * 2560);
        }
        #pragma unroll
        for (int f = 0; f < 4; ++f) {
          const short8 bfr =
              *(const short8*)&Wl[(((kbase + kb) * 4 + f) << 9) + (lane << 3)];
          acc[f] = __builtin_amdgcn_mfma_f32_32x32x16_bf16(af, bfr, acc[f], 0, 0, 0);
        }
        acc[4] = __builtin_amdgcn_mfma_f32_32x32x16_bf16(af, b4, acc[4], 0, 0, 0);
      }
    };

    // ---- xs half (K chunks 0..15) ----
    gemm_half(xs + (((size_t)b * NRB + rb) * 16 * NMB + w) * 512 + lane * 8,
              w4p, 0);

    // ---- wait: siblings' h writes of step b-1 visible (acquire) ----
    if (b) {
      if (tid == 0) {
        unsigned long long t0 = __builtin_amdgcn_s_memrealtime();
        while (__hip_atomic_load(gctr, __ATOMIC_ACQUIRE,
                                 __HIP_MEMORY_SCOPE_AGENT) < 8 * b) {
          __builtin_amdgcn_s_sleep(4);
          if (__builtin_amdgcn_s_memrealtime() - t0 > 40000000ull) break; // bail, don't hang
        }
      }
      __syncthreads();
      // ---- hs half (K chunks 16..31); read parity (b&1)^1 ----
      gemm_half(hs + (((size_t)(((b & 1) ^ 1) * 2 + d) * NRB + rb) * 16 * NMB + w)
                        * 512 + lane * 8,
                w4p + 16 * 2560, 16);
    }
    // b==0: h is zero, hs half contributes nothing -> skipped entirely.

    // ---- epilogue ----
    // C layout: col = lane&31, row = (r&3) + 8*(r>>2) + 4*(lane>>5).
    // cumsoftmax cols 0..15 live in 8-lane groups -> shfl_xor tree, no LDS.
    short* hsW = hs + ((((size_t)((b & 1) * 2 + d) * NRB + rb) * 16 + kbh) * NMB + w) * 512;
    #pragma unroll
    for (int r = 0; r < 16; ++r) {
      const int row = (r & 3) + 8 * (r >> 2) + 4 * khalf;
      float gv = acc[4][r] + c0b;            // lanes col>=16 hold 0 (zero-pad B)
      float m = gv;
      m = fmaxf(m, __shfl_xor(m, 1));
      m = fmaxf(m, __shfl_xor(m, 2));
      m = fmaxf(m, __shfl_xor(m, 4));
      const float ex = __expf(gv - m);
      float S = ex;
      S += __shfl_xor(S, 1); S += __shfl_xor(S, 2); S += __shfl_xor(S, 4);
      float P = ((lane & 7) <= s) ? ex : 0.f; // prefix mass up to chunk s
      P += __shfl_xor(P, 1); P += __shfl_xor(P, 2); P += __shfl_xor(P, 4);
      const float ratio = P / S;
      const float cin = 1.f - __shfl(ratio, khalf * 32);      // cols 0..7 group
      const float cfg = __shfl(ratio, khalf * 32 + 8);        // cols 8..15 group

      const float og = sigmoidf_(acc[0][r] + bg[0]);
      const float cg = tanh_   (acc[1][r] + bg[1]);
      const float ig = sigmoidf_(acc[2][r] + bg[2]);
      const float fg = sigmoidf_(acc[3][r] + bg[3]);
      const float ov = cfg * cin;
      const float f2 = fg * ov + (cfg - ov);
      const float i2 = ig * ov + (cin - ov);
      const float cy = f2 * creg[r] + i2 * cg;
      creg[r] = cy;
      const float hy = og * tanh_(cy);
      hsW[(size_t)(row + 32 * k8e) * 8 + ele] = f2bs(hy);
      const int t = rb * 128 + w * 32 + row;
      if (t < len_s) {
        const size_t o = (size_t)(base_s + t) * (2 * H_) + (size_t)d * H_ + e;
        if (isf) ((float*)out)[o] = hy;
        else     ((bf16*)out)[o]  = __float2bfloat16(hy);
      }
    }

    // ---- arrive: make h writes agent-visible, then signal (release) ----
    __threadfence();
    __syncthreads();
    if (tid == 0)
      __hip_atomic_fetch_add(gctr, 1, __ATOMIC_RELEASE, __HIP_MEMORY_SCOPE_AGENT);
  }

  if (b_hi < B_) {                 // per-step fallback mode: spill c carry
    #pragma unroll
    for (int r = 0; r < 16; ++r) csP[r * 64] = creg[r];
  }
}

// ---------------------------------------------------------------------------
extern "C" void kernel_launch(void* const* d_in, const int* in_sizes, int n_in,
                              void* d_out, int out_size, void* d_ws, size_t ws_size,
                              hipStream_t stream)
{
  const void* x    = d_in[0];
  const int*  sl   = (const int*)d_in[1];
  const void* W_ih = d_in[2];
  const void* b_ih = d_in[3];
  const void* W_hh = d_in[4];
  const void* b_hh = d_in[5];

  char* ws = (char*)d_ws;
  size_t off = 0;
  auto alloc = [&](size_t bytes) {
    void* p = ws + off;
    off = (off + bytes + 255) & ~(size_t)255;
    return p;
  };
  int*   meta = (int*)  alloc(128 * sizeof(int));
  short* xs   = (short*)alloc((size_t)B_ * T_ * D_ * sizeof(short));            // 32 MB
  short* Wsw  = (short*)alloc((size_t)2 * NSL * NKB * NF * 512 * sizeof(short)); // 2.6 MB
  short* hs   = (short*)alloc((size_t)2 * 2 * T_ * H_ * sizeof(short));         // 4 MB [parity][dir]
  float* bsum = (float*)alloc((size_t)G_ * sizeof(float));
  int*   ctr  = (int*)  alloc(64 * sizeof(int));
  float* cs   = (float*)alloc((size_t)2 * NSL * NRB * NMB * 1024 * sizeof(float)); // 4 MB (fallback only)
  const bool have_cs = (off <= ws_size);

  hipMemsetAsync(hs, 0, (size_t)2 * 2 * T_ * H_ * sizeof(short), stream);
  hipMemsetAsync(ctr, 0, 64 * sizeof(int), stream);

  detect_prep<<<1, 256, 0, stream>>>((const unsigned short*)x, sl, meta);
  build_bsum<<<(G_ + 255) / 256, 256, 0, stream>>>(b_ih, b_hh, bsum, meta);
  build_xs<<<(int)(((size_t)B_ * T_ * D_ / 8 + 255) / 256), 256, 0, stream>>>(x, (bf16*)xs, meta);
  build_wsw<<<(2 * NSL * NKB * NF * 64 + 255) / 256, 256, 0, stream>>>(W_ih, W_hh, (bf16*)Wsw, meta);

  // Preferred: cooperative persistent launch (co-residency guaranteed).
  int b_lo = 0, b_hi = B_;
  void* args[] = {(void*)&xs, (void*)&Wsw, (void*)&hs, (void*)&cs, (void*)&bsum,
                  (void*)&d_out, (void*)&meta, (void*)&ctr, (void*)&b_lo, (void*)&b_hi};
  hipError_t ce = hipLaunchCooperativeKernel((const void*)onlstm_persist,
                                             dim3(256), dim3(256), args, 0, stream);
  if (ce != hipSuccess) {
    (void)hipGetLastError();   // clear error state
    if (have_cs) {
      // Fallback: per-step launches; inter-step sync = kernel boundary.
      for (int b = 0; b < B_; ++b)
        onlstm_persist<<<dim3(256), dim3(256), 0, stream>>>(
            xs, Wsw, hs, cs, bsum, d_out, meta, ctr, b, b + 1);
    } else {
      // Last resort: regular persistent launch (structural residency + timeout).
      onlstm_persist<<<dim3(256), dim3(256), 0, stream>>>(
          xs, Wsw, hs, cs, bsum, d_out, meta, ctr, 0, B_);
    }
  }
}

// Round 3
// 1469.195 us; speedup vs baseline: 1.0852x; 1.0852x over previous
//
#include <hip/hip_runtime.h>
#include <hip/hip_bf16.h>

// B=32, T=2048, D=256, H=256, CS=32, N=8, G=4H+2N=1040.
// Scan over BATCH axis (32 steps), carry (T,H). Backward dir = col-reversed W_ih.
#define B_  32
#define T_  2048
#define D_  256
#define H_  256
#define G_  1040

#define NSL 8      // e-slices of width 32 (== CS; slice s == chunk n)
#define NRB 16     // row-blocks of 128 rows
#define NMB 4      // mblocks (1 per wave) of 32 rows
#define NKB 32     // K16 chunks over KK=512
#define NF  5      // B col-frags: og,cg,ig,fg (32 cols) + [cols 0..15 | zeros]
#define CTRSTRIDE 64   // ints per group counter slot (256 B) -- one cacheline each

using bf16   = __hip_bfloat16;
using short8 = __attribute__((ext_vector_type(8))) short;
using f32x16 = __attribute__((ext_vector_type(16))) float;

__device__ inline float sigmoidf_(float v) {
  return __fdividef(1.f, 1.f + __expf(-v));
}
__device__ inline float tanh_(float v) {
  v = fminf(fmaxf(v, -15.f), 15.f);
  float e = __expf(2.f * v);
  return __fdividef(e - 1.f, e + 1.f);
}
__device__ inline float bf2f(unsigned short u) {
  union { unsigned int i; float f; } c; c.i = ((unsigned int)u) << 16; return c.f;
}
__device__ inline float ldF(const void* p, size_t i, int isf) {
  return isf ? ((const float*)p)[i] : bf2f(((const unsigned short*)p)[i]);
}
__device__ inline short f2bs(float v) {
  bf16 h = __float2bfloat16(v);
  return *(short*)&h;
}

// meta: [0]=is_fp32, [8+b]=seq_len[b], [40+b]=row base[b]
__global__ __launch_bounds__(256) void detect_prep(
    const unsigned short* __restrict__ xh, const int* __restrict__ sli,
    int* __restrict__ meta)
{
  __shared__ int s_bad;
  if (threadIdx.x == 0) s_bad = 0;
  __syncthreads();
  int bad = 0;
  for (int i = threadIdx.x; i < 1024; i += 256) {
    float f = bf2f(xh[i]);
    if (!(fabsf(f) < 100.f)) bad = 1;
  }
  if (bad) atomicOr(&s_bad, 1);
  __syncthreads();
  if (threadIdx.x == 0) {
    meta[0] = s_bad;
    bool is64 = true;
    for (int i = 1; i < 32; i += 2) if (sli[i] != 0) is64 = false;
    int base = 0;
    for (int b = 0; b < B_; ++b) {
      int v = is64 ? sli[2 * b] : sli[b];
      meta[8 + b]  = v;
      meta[40 + b] = base;
      base += v;
    }
  }
}

__global__ __launch_bounds__(256) void build_bsum(
    const void* __restrict__ b_ih, const void* __restrict__ b_hh,
    float* __restrict__ bsum, const int* __restrict__ meta)
{
  const int isf = meta[0];
  int i = blockIdx.x * 256 + threadIdx.x;
  if (i < G_) bsum[i] = ldF(b_ih, i, isf) + ldF(b_hh, i, isf);
}

// xs[b][rb(16)][kbx(16)][mb(4)][lane(64)][8]: A-frag image for 32x32x16.
// This round: COALESCED loads (consecutive lanes read consecutive 32B/16B),
// scattered 16B frag-image writes (same layout, same values as before).
__global__ __launch_bounds__(256) void build_xs(
    const void* __restrict__ x, bf16* __restrict__ xs,
    const int* __restrict__ meta)
{
  const int isf = meta[0];
  size_t idx = (size_t)blockIdx.x * 256 + threadIdx.x;   // over B*T*D/8
  if (idx >= (size_t)B_ * T_ * D_ / 8) return;
  const int b  = (int)(idx >> 16);     // T*D/8 = 65536 per batch
  const int r  = (int)(idx & 65535);
  const int t  = r >> 5;               // 0..2047
  const int kc = r & 31;               // 8-elem k-chunk; k0 = kc*8
  const size_t src = ((size_t)b * T_ + t) * D_ + kc * 8;
  short8 v;
  #pragma unroll
  for (int j = 0; j < 8; ++j) v[j] = f2bs(ldF(x, src + j, isf));
  const int rb = t >> 7, mb = (t >> 5) & 3, trow = t & 31;
  const int kbx = kc >> 1, k8 = kc & 1;
  const size_t off = ((((size_t)b * 16 + rb) * 16 + kbx) * 4 + mb) * 64
                     + (k8 * 32 + trow);
  *(short8*)(xs + off * 8) = v;
}

// Wsw[d][s][kb(32)][f(5)][lane(64)][8]: B-frag image for 32x32x16
__global__ __launch_bounds__(256) void build_wsw(
    const void* __restrict__ W_ih, const void* __restrict__ W_hh,
    bf16* __restrict__ Wsw, const int* __restrict__ meta)
{
  const int isf = meta[0];
  int idx = blockIdx.x * 256 + threadIdx.x;   // over 2*8*32*5*64 = 163840
  if (idx >= 2 * NSL * NKB * NF * 64) return;
  const int lane = idx & 63;
  const int f    = (idx >> 6) % NF;
  const int kb   = (idx / (64 * NF)) % NKB;
  const int sl   = (idx / (64 * NF * NKB)) % NSL;
  const int d    = idx / (64 * NF * NKB * NSL);
  const int n    = lane & 31;
  const int k0   = kb * 16 + (lane >> 5) * 8;
  const int g = (f < 4) ? (16 + f * H_ + sl * 32 + n) : ((n < 16) ? n : -1);
  short8 v;
  #pragma unroll
  for (int j = 0; j < 8; ++j) {
    float val = 0.f;
    const int k = k0 + j;
    if (g >= 0)
      val = (k < D_) ? ldF(W_ih, (size_t)g * D_ + (d ? (D_ - 1 - k) : k), isf)
                     : ldF(W_hh, (size_t)g * H_ + (k - D_), isf);
    v[j] = f2bs(val);
  }
  *(short8*)(Wsw + (size_t)idx * 8) = v;
}

// ---------------------------------------------------------------------------
// Persistent fused recurrence. Round-3 changes (sync-contention fix):
//  - group counters padded to 256B slots (was: all 32 groups in ONE cacheline
//    -> 256 agent-scope RMWs/step serializing on one line = the 45us/step).
//  - relaxed polling + one acquire fence after the wait; release fence +
//    barrier + single release-add on arrive.
//  - epilogue: shuffle trees stage-batched across all 16 regs (ILP at
//    1 wave/SIMD), __fdividef, `out` stores deferred past the arrive.
// ---------------------------------------------------------------------------
__global__ __launch_bounds__(256, 1) void onlstm_persist(
    const short* __restrict__ xs, const short* __restrict__ Wsw,
    short* __restrict__ hs, float* __restrict__ cs,
    const float* __restrict__ bsum, void* __restrict__ out,
    const int* __restrict__ meta, int* __restrict__ ctr,
    int b_lo, int b_hi)
{
  __shared__ short Wl[NKB * 4 * 512];   // 128 KiB: frags f0..3, all 32 K-chunks

  const int tid  = threadIdx.x;
  const int lane = tid & 63;
  const int w    = tid >> 6;            // wave = mblock

  // XCD-grouped: group (rb,d) siblings (s=0..7) share lin%8 -> same XCD.
  const int lin = blockIdx.x;
  const int rb  = (lin & 7) + 8 * ((lin >> 3) >> 4);
  const int p   = (lin >> 3) & 15;
  const int d   = p >> 3;
  const int s   = p & 7;

  const int col   = lane & 31;
  const int khalf = lane >> 5;
  const int isf   = meta[0];

  const short* wsrc = Wsw + ((size_t)(d * NSL + s) * NKB) * (NF * 512);

  // ---- one-time: stage f0..3 frags into LDS (coalesced 16B/lane) ----
  for (int i = tid; i < NKB * 4 * 64; i += 256) {
    const int kb = i >> 8, rem = i & 255, f = rem >> 6, l = rem & 63;
    *(short8*)&Wl[((kb * 4 + f) << 9) + (l << 3)] =
        *(const short8*)(wsrc + ((kb * 5 + f) << 9) + (l << 3));
  }
  __syncthreads();

  // bias preloads (L1/L2 hits)
  float bg[4];
  #pragma unroll
  for (int f = 0; f < 4; ++f) bg[f] = bsum[16 + f * H_ + s * 32 + col];
  const float c0b = (col < 16) ? bsum[col] : 0.f;

  // epilogue addressing for e = s*32+col
  const int e   = s * 32 + col;
  const int k8e = (e >> 3) & 1, ele = e & 7, kbh = e >> 4;

  int* gctr = ctr + (size_t)(d * NRB + rb) * CTRSTRIDE;  // private cacheline
  const short* w4p = wsrc + 4 * 512 + lane * 8;   // f4 frag, stride 5*512/chunk

  float* csP = cs + (((size_t)(d * NSL + s) * NRB + rb) * NMB + w) * 1024 + lane;

  f32x16 creg;                                    // c carry: registers
  if (b_lo > 0) {
    #pragma unroll
    for (int r = 0; r < 16; ++r) creg[r] = csP[r * 64];
  } else {
    #pragma unroll
    for (int r = 0; r < 16; ++r) creg[r] = 0.f;
  }

  for (int b = b_lo; b < b_hi; ++b) {
    const int len_s  = meta[8 + b];
    const int base_s = meta[40 + b];

    f32x16 acc[NF];
    #pragma unroll
    for (int f = 0; f < NF; ++f)
      #pragma unroll
      for (int r = 0; r < 16; ++r) acc[f][r] = 0.f;

    // barrier-free GEMM half: 16 chunks, A + f4 pipelined 3 deep from global,
    // f0..3 from LDS-resident W.
    auto gemm_half = [&](const short* aPtr, const short* w4q, const int kbase) {
      short8 a0 = *(const short8*)(aPtr);
      short8 a1 = *(const short8*)(aPtr + 2048);
      short8 a2 = *(const short8*)(aPtr + 4096);
      short8 q0 = *(const short8*)(w4q);
      short8 q1 = *(const short8*)(w4q + 2560);
      short8 q2 = *(const short8*)(w4q + 5120);
      #pragma unroll
      for (int kb = 0; kb < 16; ++kb) {
        const short8 af = a0, b4 = q0;
        a0 = a1; a1 = a2; q0 = q1; q1 = q2;
        if (kb < 13) {
          a2 = *(const short8*)(aPtr + (kb + 3) * 2048);
          q2 = *(const short8*)(w4q + (kb + 3) * 2560);
        }
        #pragma unroll
        for (int f = 0; f < 4; ++f) {
          const short8 bfr =
              *(const short8*)&Wl[(((kbase + kb) * 4 + f) << 9) + (lane << 3)];
          acc[f] = __builtin_amdgcn_mfma_f32_32x32x16_bf16(af, bfr, acc[f], 0, 0, 0);
        }
        acc[4] = __builtin_amdgcn_mfma_f32_32x32x16_bf16(af, b4, acc[4], 0, 0, 0);
      }
    };

    // ---- xs half (K chunks 0..15); overlaps siblings' step b-1 tails ----
    gemm_half(xs + (((size_t)b * NRB + rb) * 16 * NMB + w) * 512 + lane * 8,
              w4p, 0);

    // ---- wait: siblings' h writes of step b-1 visible ----
    if (b) {
      if (tid == 0) {
        unsigned long long t0 = __builtin_amdgcn_s_memrealtime();
        while (__hip_atomic_load(gctr, __ATOMIC_RELAXED,
                                 __HIP_MEMORY_SCOPE_AGENT) < 8 * b) {
          __builtin_amdgcn_s_sleep(1);
          if (__builtin_amdgcn_s_memrealtime() - t0 > 40000000ull) break; // no hang
        }
      }
      __syncthreads();
      __builtin_amdgcn_fence(__ATOMIC_ACQUIRE, "agent");   // all threads acquire
      // ---- hs half (K chunks 16..31); read parity (b&1)^1 ----
      gemm_half(hs + (((size_t)(((b & 1) ^ 1) * 2 + d) * NRB + rb) * 16 * NMB + w)
                        * 512 + lane * 8,
                w4p + 16 * 2560, 16);
    }
    // b==0: h is zero, hs half contributes nothing -> skipped entirely.

    // ---- epilogue ----
    // C layout: col = lane&31, row = (r&3) + 8*(r>>2) + 4*(lane>>5).
    // Stage-batched shuffle trees: 16 independent chains per stage (ILP).
    f32x16 gv, mx, ex, Sv, Pv, rat;
    #pragma unroll
    for (int r = 0; r < 16; ++r) gv[r] = acc[4][r] + c0b;  // cols>=16: exactly 0
    #pragma unroll
    for (int r = 0; r < 16; ++r) mx[r] = gv[r];
    #pragma unroll
    for (int r = 0; r < 16; ++r) { float t = __shfl_xor(mx[r], 1); mx[r] = fmaxf(mx[r], t); }
    #pragma unroll
    for (int r = 0; r < 16; ++r) { float t = __shfl_xor(mx[r], 2); mx[r] = fmaxf(mx[r], t); }
    #pragma unroll
    for (int r = 0; r < 16; ++r) { float t = __shfl_xor(mx[r], 4); mx[r] = fmaxf(mx[r], t); }
    #pragma unroll
    for (int r = 0; r < 16; ++r) ex[r] = __expf(gv[r] - mx[r]);
    const bool pin = (lane & 7) <= s;
    #pragma unroll
    for (int r = 0; r < 16; ++r) { Sv[r] = ex[r]; Pv[r] = pin ? ex[r] : 0.f; }
    #pragma unroll
    for (int r = 0; r < 16; ++r) { Sv[r] += __shfl_xor(Sv[r], 1); Pv[r] += __shfl_xor(Pv[r], 1); }
    #pragma unroll
    for (int r = 0; r < 16; ++r) { Sv[r] += __shfl_xor(Sv[r], 2); Pv[r] += __shfl_xor(Pv[r], 2); }
    #pragma unroll
    for (int r = 0; r < 16; ++r) { Sv[r] += __shfl_xor(Sv[r], 4); Pv[r] += __shfl_xor(Pv[r], 4); }
    #pragma unroll
    for (int r = 0; r < 16; ++r) rat[r] = __fdividef(Pv[r], Sv[r]);
    f32x16 cinv, cfgv;
    #pragma unroll
    for (int r = 0; r < 16; ++r) cinv[r] = 1.f - __shfl(rat[r], khalf * 32);
    #pragma unroll
    for (int r = 0; r < 16; ++r) cfgv[r] = __shfl(rat[r], khalf * 32 + 8);

    short* hsW = hs + ((((size_t)((b & 1) * 2 + d) * NRB + rb) * 16 + kbh) * NMB + w) * 512;
    f32x16 hyv;
    #pragma unroll
    for (int r = 0; r < 16; ++r) {
      const int row = (r & 3) + 8 * (r >> 2) + 4 * khalf;
      const float cin = cinv[r];
      const float cfg = cfgv[r];
      const float og = sigmoidf_(acc[0][r] + bg[0]);
      const float cg = tanh_   (acc[1][r] + bg[1]);
      const float ig = sigmoidf_(acc[2][r] + bg[2]);
      const float fg = sigmoidf_(acc[3][r] + bg[3]);
      const float ov = cfg * cin;
      const float f2 = fg * ov + (cfg - ov);
      const float i2 = ig * ov + (cin - ov);
      const float cy = f2 * creg[r] + i2 * cg;
      creg[r] = cy;
      const float hy = og * tanh_(cy);
      hyv[r] = hy;
      hsW[(size_t)(row + 32 * k8e) * 8 + ele] = f2bs(hy);   // fire & forget
    }

    // ---- arrive: h writes visible (release), then signal ----
    __builtin_amdgcn_fence(__ATOMIC_RELEASE, "agent");
    __syncthreads();
    if (tid == 0)
      __hip_atomic_fetch_add(gctr, 1, __ATOMIC_RELEASE, __HIP_MEMORY_SCOPE_AGENT);

    // ---- deferred out stores: drain under next step's xs GEMM ----
    #pragma unroll
    for (int r = 0; r < 16; ++r) {
      const int row = (r & 3) + 8 * (r >> 2) + 4 * khalf;
      const int t = rb * 128 + w * 32 + row;
      if (t < len_s) {
        const size_t o = (size_t)(base_s + t) * (2 * H_) + (size_t)d * H_ + e;
        if (isf) ((float*)out)[o] = hyv[r];
        else     ((bf16*)out)[o]  = __float2bfloat16(hyv[r]);
      }
    }
  }

  if (b_hi < B_) {                 // per-step fallback mode: spill c carry
    #pragma unroll
    for (int r = 0; r < 16; ++r) csP[r * 64] = creg[r];
  }
}

// ---------------------------------------------------------------------------
extern "C" void kernel_launch(void* const* d_in, const int* in_sizes, int n_in,
                              void* d_out, int out_size, void* d_ws, size_t ws_size,
                              hipStream_t stream)
{
  const void* x    = d_in[0];
  const int*  sl   = (const int*)d_in[1];
  const void* W_ih = d_in[2];
  const void* b_ih = d_in[3];
  const void* W_hh = d_in[4];
  const void* b_hh = d_in[5];

  char* ws = (char*)d_ws;
  size_t off = 0;
  auto alloc = [&](size_t bytes) {
    void* p = ws + off;
    off = (off + bytes + 255) & ~(size_t)255;
    return p;
  };
  int*   meta = (int*)  alloc(128 * sizeof(int));
  short* xs   = (short*)alloc((size_t)B_ * T_ * D_ * sizeof(short));            // 32 MB
  short* Wsw  = (short*)alloc((size_t)2 * NSL * NKB * NF * 512 * sizeof(short)); // 2.6 MB
  short* hs   = (short*)alloc((size_t)2 * 2 * T_ * H_ * sizeof(short));         // 4 MB [parity][dir]
  float* bsum = (float*)alloc((size_t)G_ * sizeof(float));
  int*   ctr  = (int*)  alloc((size_t)32 * CTRSTRIDE * sizeof(int));            // padded: 1 line/group
  float* cs   = (float*)alloc((size_t)2 * NSL * NRB * NMB * 1024 * sizeof(float)); // 4 MB (fallback only)
  const bool have_cs = (off <= ws_size);

  hipMemsetAsync(hs, 0, (size_t)2 * 2 * T_ * H_ * sizeof(short), stream);
  hipMemsetAsync(ctr, 0, (size_t)32 * CTRSTRIDE * sizeof(int), stream);

  detect_prep<<<1, 256, 0, stream>>>((const unsigned short*)x, sl, meta);
  build_bsum<<<(G_ + 255) / 256, 256, 0, stream>>>(b_ih, b_hh, bsum, meta);
  build_xs<<<(int)(((size_t)B_ * T_ * D_ / 8 + 255) / 256), 256, 0, stream>>>(x, (bf16*)xs, meta);
  build_wsw<<<(2 * NSL * NKB * NF * 64 + 255) / 256, 256, 0, stream>>>(W_ih, W_hh, (bf16*)Wsw, meta);

  // Preferred: cooperative persistent launch (co-residency guaranteed).
  int b_lo = 0, b_hi = B_;
  void* args[] = {(void*)&xs, (void*)&Wsw, (void*)&hs, (void*)&cs, (void*)&bsum,
                  (void*)&d_out, (void*)&meta, (void*)&ctr, (void*)&b_lo, (void*)&b_hi};
  hipError_t ce = hipLaunchCooperativeKernel((const void*)onlstm_persist,
                                             dim3(256), dim3(256), args, 0, stream);
  if (ce != hipSuccess) {
    (void)hipGetLastError();   // clear error state
    if (have_cs) {
      // Fallback: per-step launches; inter-step sync = kernel boundary.
      for (int b = 0; b < B_; ++b)
        onlstm_persist<<<dim3(256), dim3(256), 0, stream>>>(
            xs, Wsw, hs, cs, bsum, d_out, meta, ctr, b, b + 1);
    } else {
      // Last resort: regular persistent launch (structural residency + timeout).
      onlstm_persist<<<dim3(256), dim3(256), 0, stream>>>(
          xs, Wsw, hs, cs, bsum, d_out, meta, ctr, 0, B_);
    }
  }
}

// Round 4
// 849.157 us; speedup vs baseline: 1.8777x; 1.7302x over previous
//
#include <hip/hip_runtime.h>
#include <hip/hip_bf16.h>

// B=32, T=2048, D=256, H=256, CS=32, N=8, G=4H+2N=1040.
// Scan over BATCH axis (32 steps), carry (T,H). Backward dir = col-reversed W_ih.
#define B_  32
#define T_  2048
#define D_  256
#define H_  256
#define G_  1040

#define NSL 8      // e-slices of width 32 (== CS; slice s == chunk n)
#define NRB 16     // row-blocks of 128 rows
#define NMB 4      // mblocks (1 per wave) of 32 rows
#define NKB 32     // K16 chunks over KK=512
#define NF  5      // B col-frags: og,cg,ig,fg (32 cols) + [cols 0..15 | zeros]
#define CTRSTRIDE 64   // ints per group counter slot (256 B) -- one cacheline each

using bf16   = __hip_bfloat16;
using short8 = __attribute__((ext_vector_type(8))) short;
using f32x16 = __attribute__((ext_vector_type(16))) float;

__device__ inline float sigmoidf_(float v) {
  return __fdividef(1.f, 1.f + __expf(-v));
}
__device__ inline float tanh_(float v) {
  v = fminf(fmaxf(v, -15.f), 15.f);
  float e = __expf(2.f * v);
  return __fdividef(e - 1.f, e + 1.f);
}
__device__ inline float bf2f(unsigned short u) {
  union { unsigned int i; float f; } c; c.i = ((unsigned int)u) << 16; return c.f;
}
__device__ inline float ldF(const void* p, size_t i, int isf) {
  return isf ? ((const float*)p)[i] : bf2f(((const unsigned short*)p)[i]);
}
__device__ inline short f2bs(float v) {
  bf16 h = __float2bfloat16(v);
  return *(short*)&h;
}

// meta: [0]=is_fp32, [8+b]=seq_len[b], [40+b]=row base[b]
__global__ __launch_bounds__(256) void detect_prep(
    const unsigned short* __restrict__ xh, const int* __restrict__ sli,
    int* __restrict__ meta)
{
  __shared__ int s_bad;
  if (threadIdx.x == 0) s_bad = 0;
  __syncthreads();
  int bad = 0;
  for (int i = threadIdx.x; i < 1024; i += 256) {
    float f = bf2f(xh[i]);
    if (!(fabsf(f) < 100.f)) bad = 1;
  }
  if (bad) atomicOr(&s_bad, 1);
  __syncthreads();
  if (threadIdx.x == 0) {
    meta[0] = s_bad;
    bool is64 = true;
    for (int i = 1; i < 32; i += 2) if (sli[i] != 0) is64 = false;
    int base = 0;
    for (int b = 0; b < B_; ++b) {
      int v = is64 ? sli[2 * b] : sli[b];
      meta[8 + b]  = v;
      meta[40 + b] = base;
      base += v;
    }
  }
}

__global__ __launch_bounds__(256) void build_bsum(
    const void* __restrict__ b_ih, const void* __restrict__ b_hh,
    float* __restrict__ bsum, const int* __restrict__ meta)
{
  const int isf = meta[0];
  int i = blockIdx.x * 256 + threadIdx.x;
  if (i < G_) bsum[i] = ldF(b_ih, i, isf) + ldF(b_hh, i, isf);
}

// xs[b][rb(16)][kbx(16)][mb(4)][lane(64)][8]: A-frag image for 32x32x16.
// Coalesced loads, scattered 16B frag-image writes.
__global__ __launch_bounds__(256) void build_xs(
    const void* __restrict__ x, bf16* __restrict__ xs,
    const int* __restrict__ meta)
{
  const int isf = meta[0];
  size_t idx = (size_t)blockIdx.x * 256 + threadIdx.x;   // over B*T*D/8
  if (idx >= (size_t)B_ * T_ * D_ / 8) return;
  const int b  = (int)(idx >> 16);     // T*D/8 = 65536 per batch
  const int r  = (int)(idx & 65535);
  const int t  = r >> 5;               // 0..2047
  const int kc = r & 31;               // 8-elem k-chunk; k0 = kc*8
  const size_t src = ((size_t)b * T_ + t) * D_ + kc * 8;
  short8 v;
  #pragma unroll
  for (int j = 0; j < 8; ++j) v[j] = f2bs(ldF(x, src + j, isf));
  const int rb = t >> 7, mb = (t >> 5) & 3, trow = t & 31;
  const int kbx = kc >> 1, k8 = kc & 1;
  const size_t off = ((((size_t)b * 16 + rb) * 16 + kbx) * 4 + mb) * 64
                     + (k8 * 32 + trow);
  *(short8*)(xs + off * 8) = v;
}

// Wsw[d][s][kb(32)][f(5)][lane(64)][8]: B-frag image for 32x32x16
__global__ __launch_bounds__(256) void build_wsw(
    const void* __restrict__ W_ih, const void* __restrict__ W_hh,
    bf16* __restrict__ Wsw, const int* __restrict__ meta)
{
  const int isf = meta[0];
  int idx = blockIdx.x * 256 + threadIdx.x;   // over 2*8*32*5*64 = 163840
  if (idx >= 2 * NSL * NKB * NF * 64) return;
  const int lane = idx & 63;
  const int f    = (idx >> 6) % NF;
  const int kb   = (idx / (64 * NF)) % NKB;
  const int sl   = (idx / (64 * NF * NKB)) % NSL;
  const int d    = idx / (64 * NF * NKB * NSL);
  const int n    = lane & 31;
  const int k0   = kb * 16 + (lane >> 5) * 8;
  const int g = (f < 4) ? (16 + f * H_ + sl * 32 + n) : ((n < 16) ? n : -1);
  short8 v;
  #pragma unroll
  for (int j = 0; j < 8; ++j) {
    float val = 0.f;
    const int k = k0 + j;
    if (g >= 0)
      val = (k < D_) ? ldF(W_ih, (size_t)g * D_ + (d ? (D_ - 1 - k) : k), isf)
                     : ldF(W_hh, (size_t)g * H_ + (k - D_), isf);
    v[j] = f2bs(val);
  }
  *(short8*)(Wsw + (size_t)idx * 8) = v;
}

// ---------------------------------------------------------------------------
// Persistent fused recurrence. Round-4 change: ONE cache-maintenance op per
// block per step instead of 8 waves' worth.
//  - acquire: tid0-only agent fence (1 buffer_inv: CU-L1 + XCD-L2 physical
//    invalidate) + __syncthreads -> all waves' post-barrier loads are fresh.
//  - release: __syncthreads (compiler drains vmcnt(0) before s_barrier, so
//    all waves' hs stores are in L2) + tid0 RELEASE fetch_add (1 buffer_wbl2).
//  Round-3's all-thread fences = 16 serialized inv/wbl2 per block-step = the
//  ~30 us/step stall (MfmaUtil 5%, VALU 10%, HBM 1.7% -> pure wait).
// ---------------------------------------------------------------------------
__global__ __launch_bounds__(256, 1) void onlstm_persist(
    const short* __restrict__ xs, const short* __restrict__ Wsw,
    short* __restrict__ hs, float* __restrict__ cs,
    const float* __restrict__ bsum, void* __restrict__ out,
    const int* __restrict__ meta, int* __restrict__ ctr,
    int b_lo, int b_hi)
{
  __shared__ short Wl[NKB * 4 * 512];   // 128 KiB: frags f0..3, all 32 K-chunks

  const int tid  = threadIdx.x;
  const int lane = tid & 63;
  const int w    = tid >> 6;            // wave = mblock

  // XCD-grouped: group (rb,d) siblings (s=0..7) share lin%8 -> same XCD.
  const int lin = blockIdx.x;
  const int rb  = (lin & 7) + 8 * ((lin >> 3) >> 4);
  const int p   = (lin >> 3) & 15;
  const int d   = p >> 3;
  const int s   = p & 7;

  const int col   = lane & 31;
  const int khalf = lane >> 5;
  const int isf   = meta[0];

  const short* wsrc = Wsw + ((size_t)(d * NSL + s) * NKB) * (NF * 512);

  // ---- one-time: stage f0..3 frags into LDS (coalesced 16B/lane) ----
  for (int i = tid; i < NKB * 4 * 64; i += 256) {
    const int kb = i >> 8, rem = i & 255, f = rem >> 6, l = rem & 63;
    *(short8*)&Wl[((kb * 4 + f) << 9) + (l << 3)] =
        *(const short8*)(wsrc + ((kb * 5 + f) << 9) + (l << 3));
  }
  __syncthreads();

  // bias preloads (L1/L2 hits)
  float bg[4];
  #pragma unroll
  for (int f = 0; f < 4; ++f) bg[f] = bsum[16 + f * H_ + s * 32 + col];
  const float c0b = (col < 16) ? bsum[col] : 0.f;

  // epilogue addressing for e = s*32+col
  const int e   = s * 32 + col;
  const int k8e = (e >> 3) & 1, ele = e & 7, kbh = e >> 4;

  int* gctr = ctr + (size_t)(d * NRB + rb) * CTRSTRIDE;  // private cacheline
  const short* w4p = wsrc + 4 * 512 + lane * 8;   // f4 frag, stride 5*512/chunk

  float* csP = cs + (((size_t)(d * NSL + s) * NRB + rb) * NMB + w) * 1024 + lane;

  f32x16 creg;                                    // c carry: registers
  if (b_lo > 0) {
    #pragma unroll
    for (int r = 0; r < 16; ++r) creg[r] = csP[r * 64];
  } else {
    #pragma unroll
    for (int r = 0; r < 16; ++r) creg[r] = 0.f;
  }

  for (int b = b_lo; b < b_hi; ++b) {
    const int len_s  = meta[8 + b];
    const int base_s = meta[40 + b];

    f32x16 acc[NF];
    #pragma unroll
    for (int f = 0; f < NF; ++f)
      #pragma unroll
      for (int r = 0; r < 16; ++r) acc[f][r] = 0.f;

    // barrier-free GEMM half: 16 chunks, A + f4 pipelined 3 deep from global,
    // f0..3 from LDS-resident W.
    auto gemm_half = [&](const short* aPtr, const short* w4q, const int kbase) {
      short8 a0 = *(const short8*)(aPtr);
      short8 a1 = *(const short8*)(aPtr + 2048);
      short8 a2 = *(const short8*)(aPtr + 4096);
      short8 q0 = *(const short8*)(w4q);
      short8 q1 = *(const short8*)(w4q + 2560);
      short8 q2 = *(const short8*)(w4q + 5120);
      #pragma unroll
      for (int kb = 0; kb < 16; ++kb) {
        const short8 af = a0, b4 = q0;
        a0 = a1; a1 = a2; q0 = q1; q1 = q2;
        if (kb < 13) {
          a2 = *(const short8*)(aPtr + (kb + 3) * 2048);
          q2 = *(const short8*)(w4q + (kb + 3) * 2560);
        }
        #pragma unroll
        for (int f = 0; f < 4; ++f) {
          const short8 bfr =
              *(const short8*)&Wl[(((kbase + kb) * 4 + f) << 9) + (lane << 3)];
          acc[f] = __builtin_amdgcn_mfma_f32_32x32x16_bf16(af, bfr, acc[f], 0, 0, 0);
        }
        acc[4] = __builtin_amdgcn_mfma_f32_32x32x16_bf16(af, b4, acc[4], 0, 0, 0);
      }
    };

    // ---- xs half (K chunks 0..15); overlaps siblings' step b-1 tails ----
    gemm_half(xs + (((size_t)b * NRB + rb) * 16 * NMB + w) * 512 + lane * 8,
              w4p, 0);

    // ---- wait: siblings' h writes of step b-1 visible ----
    if (b) {
      if (tid == 0) {
        unsigned long long t0 = __builtin_amdgcn_s_memrealtime();
        while (__hip_atomic_load(gctr, __ATOMIC_RELAXED,
                                 __HIP_MEMORY_SCOPE_AGENT) < 8 * b) {
          __builtin_amdgcn_s_sleep(1);
          if (__builtin_amdgcn_s_memrealtime() - t0 > 40000000ull) break; // no hang
        }
        // ONE acquire per block: invalidates CU-L1 + XCD-L2 physically;
        // barrier below publishes the fresh view to the other 3 waves.
        __builtin_amdgcn_fence(__ATOMIC_ACQUIRE, "agent");
      }
      __syncthreads();
      // ---- hs half (K chunks 16..31); read parity (b&1)^1 ----
      gemm_half(hs + (((size_t)(((b & 1) ^ 1) * 2 + d) * NRB + rb) * 16 * NMB + w)
                        * 512 + lane * 8,
                w4p + 16 * 2560, 16);
    }
    // b==0: h is zero, hs half contributes nothing -> skipped entirely.

    // ---- epilogue ----
    // C layout: col = lane&31, row = (r&3) + 8*(r>>2) + 4*(lane>>5).
    // Stage-batched shuffle trees (16 parallel chains); buffers reused
    // in place to keep peak live registers low.
    f32x16 gv, mx, Sv, Pv;
    #pragma unroll
    for (int r = 0; r < 16; ++r) gv[r] = acc[4][r] + c0b;  // cols>=16: exactly 0
    #pragma unroll
    for (int r = 0; r < 16; ++r) mx[r] = gv[r];
    #pragma unroll
    for (int r = 0; r < 16; ++r) { float t = __shfl_xor(mx[r], 1); mx[r] = fmaxf(mx[r], t); }
    #pragma unroll
    for (int r = 0; r < 16; ++r) { float t = __shfl_xor(mx[r], 2); mx[r] = fmaxf(mx[r], t); }
    #pragma unroll
    for (int r = 0; r < 16; ++r) { float t = __shfl_xor(mx[r], 4); mx[r] = fmaxf(mx[r], t); }
    #pragma unroll
    for (int r = 0; r < 16; ++r) gv[r] = __expf(gv[r] - mx[r]);   // gv := ex
    const bool pin = (lane & 7) <= s;
    #pragma unroll
    for (int r = 0; r < 16; ++r) { Sv[r] = gv[r]; Pv[r] = pin ? gv[r] : 0.f; }
    #pragma unroll
    for (int r = 0; r < 16; ++r) { Sv[r] += __shfl_xor(Sv[r], 1); Pv[r] += __shfl_xor(Pv[r], 1); }
    #pragma unroll
    for (int r = 0; r < 16; ++r) { Sv[r] += __shfl_xor(Sv[r], 2); Pv[r] += __shfl_xor(Pv[r], 2); }
    #pragma unroll
    for (int r = 0; r < 16; ++r) { Sv[r] += __shfl_xor(Sv[r], 4); Pv[r] += __shfl_xor(Pv[r], 4); }
    #pragma unroll
    for (int r = 0; r < 16; ++r) Pv[r] = __fdividef(Pv[r], Sv[r]);  // Pv := ratio
    f32x16 cinv, cfgv;
    #pragma unroll
    for (int r = 0; r < 16; ++r) cinv[r] = 1.f - __shfl(Pv[r], khalf * 32);
    #pragma unroll
    for (int r = 0; r < 16; ++r) cfgv[r] = __shfl(Pv[r], khalf * 32 + 8);

    short* hsW = hs + ((((size_t)((b & 1) * 2 + d) * NRB + rb) * 16 + kbh) * NMB + w) * 512;
    f32x16 hyv;
    #pragma unroll
    for (int r = 0; r < 16; ++r) {
      const int row = (r & 3) + 8 * (r >> 2) + 4 * khalf;
      const float cin = cinv[r];
      const float cfg = cfgv[r];
      const float og = sigmoidf_(acc[0][r] + bg[0]);
      const float cg = tanh_   (acc[1][r] + bg[1]);
      const float ig = sigmoidf_(acc[2][r] + bg[2]);
      const float fg = sigmoidf_(acc[3][r] + bg[3]);
      const float ov = cfg * cin;
      const float f2 = fg * ov + (cfg - ov);
      const float i2 = ig * ov + (cin - ov);
      const float cy = f2 * creg[r] + i2 * cg;
      creg[r] = cy;
      const float hy = og * tanh_(cy);
      hyv[r] = hy;
      hsW[(size_t)(row + 32 * k8e) * 8 + ele] = f2bs(hy);   // fire & forget
    }

    // ---- arrive: barrier drains all waves' stores to L2 (vmcnt(0) before
    // s_barrier), then ONE release-add (single buffer_wbl2) publishes them.
    __syncthreads();
    if (tid == 0)
      __hip_atomic_fetch_add(gctr, 1, __ATOMIC_RELEASE, __HIP_MEMORY_SCOPE_AGENT);

    // ---- deferred out stores: drain under next step's xs GEMM ----
    #pragma unroll
    for (int r = 0; r < 16; ++r) {
      const int row = (r & 3) + 8 * (r >> 2) + 4 * khalf;
      const int t = rb * 128 + w * 32 + row;
      if (t < len_s) {
        const size_t o = (size_t)(base_s + t) * (2 * H_) + (size_t)d * H_ + e;
        if (isf) ((float*)out)[o] = hyv[r];
        else     ((bf16*)out)[o]  = __float2bfloat16(hyv[r]);
      }
    }
  }

  if (b_hi < B_) {                 // per-step fallback mode: spill c carry
    #pragma unroll
    for (int r = 0; r < 16; ++r) csP[r * 64] = creg[r];
  }
}

// ---------------------------------------------------------------------------
extern "C" void kernel_launch(void* const* d_in, const int* in_sizes, int n_in,
                              void* d_out, int out_size, void* d_ws, size_t ws_size,
                              hipStream_t stream)
{
  const void* x    = d_in[0];
  const int*  sl   = (const int*)d_in[1];
  const void* W_ih = d_in[2];
  const void* b_ih = d_in[3];
  const void* W_hh = d_in[4];
  const void* b_hh = d_in[5];

  char* ws = (char*)d_ws;
  size_t off = 0;
  auto alloc = [&](size_t bytes) {
    void* p = ws + off;
    off = (off + bytes + 255) & ~(size_t)255;
    return p;
  };
  int*   meta = (int*)  alloc(128 * sizeof(int));
  short* xs   = (short*)alloc((size_t)B_ * T_ * D_ * sizeof(short));            // 32 MB
  short* Wsw  = (short*)alloc((size_t)2 * NSL * NKB * NF * 512 * sizeof(short)); // 2.6 MB
  short* hs   = (short*)alloc((size_t)2 * 2 * T_ * H_ * sizeof(short));         // 4 MB [parity][dir]
  float* bsum = (float*)alloc((size_t)G_ * sizeof(float));
  int*   ctr  = (int*)  alloc((size_t)32 * CTRSTRIDE * sizeof(int));            // padded: 1 line/group
  float* cs   = (float*)alloc((size_t)2 * NSL * NRB * NMB * 1024 * sizeof(float)); // 4 MB (fallback only)
  const bool have_cs = (off <= ws_size);

  hipMemsetAsync(hs, 0, (size_t)2 * 2 * T_ * H_ * sizeof(short), stream);
  hipMemsetAsync(ctr, 0, (size_t)32 * CTRSTRIDE * sizeof(int), stream);

  detect_prep<<<1, 256, 0, stream>>>((const unsigned short*)x, sl, meta);
  build_bsum<<<(G_ + 255) / 256, 256, 0, stream>>>(b_ih, b_hh, bsum, meta);
  build_xs<<<(int)(((size_t)B_ * T_ * D_ / 8 + 255) / 256), 256, 0, stream>>>(x, (bf16*)xs, meta);
  build_wsw<<<(2 * NSL * NKB * NF * 64 + 255) / 256, 256, 0, stream>>>(W_ih, W_hh, (bf16*)Wsw, meta);

  // Preferred: cooperative persistent launch (co-residency guaranteed).
  int b_lo = 0, b_hi = B_;
  void* args[] = {(void*)&xs, (void*)&Wsw, (void*)&hs, (void*)&cs, (void*)&bsum,
                  (void*)&d_out, (void*)&meta, (void*)&ctr, (void*)&b_lo, (void*)&b_hi};
  hipError_t ce = hipLaunchCooperativeKernel((const void*)onlstm_persist,
                                             dim3(256), dim3(256), args, 0, stream);
  if (ce != hipSuccess) {
    (void)hipGetLastError();   // clear error state
    if (have_cs) {
      // Fallback: per-step launches; inter-step sync = kernel boundary.
      for (int b = 0; b < B_; ++b)
        onlstm_persist<<<dim3(256), dim3(256), 0, stream>>>(
            xs, Wsw, hs, cs, bsum, d_out, meta, ctr, b, b + 1);
    } else {
      // Last resort: regular persistent launch (structural residency + timeout).
      onlstm_persist<<<dim3(256), dim3(256), 0, stream>>>(
          xs, Wsw, hs, cs, bsum, d_out, meta, ctr, 0, B_);
    }
  }
}

// Round 5
// 676.213 us; speedup vs baseline: 2.3579x; 1.2558x over previous
//
#include <hip/hip_runtime.h>
#include <hip/hip_bf16.h>

// B=32, T=2048, D=256, H=256, CS=32, N=8, G=4H+2N=1040.
// Scan over BATCH axis (32 steps), carry (T,H). Backward dir = col-reversed W_ih.
#define B_  32
#define T_  2048
#define D_  256
#define H_  256
#define G_  1040

#define NSL 8      // e-slices of width 32 (== CS; slice s == chunk n)
#define NRB 16     // row-blocks of 128 rows
#define NMB 4      // mblocks (1 per wave) of 32 rows
#define NKB 32     // K16 chunks over KK=512
#define NF  5      // B col-frags: og,cg,ig,fg (32 cols) + [cols 0..15 | zeros]
#define CTRSTRIDE 64   // ints per group counter slot (256 B)

using bf16   = __hip_bfloat16;
using short8 = __attribute__((ext_vector_type(8))) short;
using f32x16 = __attribute__((ext_vector_type(16))) float;
using ull    = unsigned long long;

__device__ inline float sigmoidf_(float v) {
  return __fdividef(1.f, 1.f + __expf(-v));
}
__device__ inline float tanh_(float v) {
  v = fminf(fmaxf(v, -15.f), 15.f);
  float e = __expf(2.f * v);
  return __fdividef(e - 1.f, e + 1.f);
}
__device__ inline float bf2f(unsigned short u) {
  union { unsigned int i; float f; } c; c.i = ((unsigned int)u) << 16; return c.f;
}
__device__ inline float ldF(const void* p, size_t i, int isf) {
  return isf ? ((const float*)p)[i] : bf2f(((const unsigned short*)p)[i]);
}
__device__ inline short f2bs(float v) {
  bf16 h = __float2bfloat16(v);
  return *(short*)&h;
}

// meta: [0]=is_fp32, [8+b]=seq_len[b], [40+b]=row base[b]
__global__ __launch_bounds__(256) void detect_prep(
    const unsigned short* __restrict__ xh, const int* __restrict__ sli,
    int* __restrict__ meta)
{
  __shared__ int s_bad;
  if (threadIdx.x == 0) s_bad = 0;
  __syncthreads();
  int bad = 0;
  for (int i = threadIdx.x; i < 1024; i += 256) {
    float f = bf2f(xh[i]);
    if (!(fabsf(f) < 100.f)) bad = 1;
  }
  if (bad) atomicOr(&s_bad, 1);
  __syncthreads();
  if (threadIdx.x == 0) {
    meta[0] = s_bad;
    bool is64 = true;
    for (int i = 1; i < 32; i += 2) if (sli[i] != 0) is64 = false;
    int base = 0;
    for (int b = 0; b < B_; ++b) {
      int v = is64 ? sli[2 * b] : sli[b];
      meta[8 + b]  = v;
      meta[40 + b] = base;
      base += v;
    }
  }
}

__global__ __launch_bounds__(256) void build_bsum(
    const void* __restrict__ b_ih, const void* __restrict__ b_hh,
    float* __restrict__ bsum, const int* __restrict__ meta)
{
  const int isf = meta[0];
  int i = blockIdx.x * 256 + threadIdx.x;
  if (i < G_) bsum[i] = ldF(b_ih, i, isf) + ldF(b_hh, i, isf);
}

// xs[b][rb(16)][kbx(16)][mb(4)][lane(64)][8]: A-frag image for 32x32x16.
// Coalesced loads, scattered 16B frag-image writes.
__global__ __launch_bounds__(256) void build_xs(
    const void* __restrict__ x, bf16* __restrict__ xs,
    const int* __restrict__ meta)
{
  const int isf = meta[0];
  size_t idx = (size_t)blockIdx.x * 256 + threadIdx.x;   // over B*T*D/8
  if (idx >= (size_t)B_ * T_ * D_ / 8) return;
  const int b  = (int)(idx >> 16);     // T*D/8 = 65536 per batch
  const int r  = (int)(idx & 65535);
  const int t  = r >> 5;               // 0..2047
  const int kc = r & 31;               // 8-elem k-chunk; k0 = kc*8
  const size_t src = ((size_t)b * T_ + t) * D_ + kc * 8;
  short8 v;
  #pragma unroll
  for (int j = 0; j < 8; ++j) v[j] = f2bs(ldF(x, src + j, isf));
  const int rb = t >> 7, mb = (t >> 5) & 3, trow = t & 31;
  const int kbx = kc >> 1, k8 = kc & 1;
  const size_t off = ((((size_t)b * 16 + rb) * 16 + kbx) * 4 + mb) * 64
                     + (k8 * 32 + trow);
  *(short8*)(xs + off * 8) = v;
}

// Wsw[d][s][kb(32)][f(5)][lane(64)][8]: B-frag image for 32x32x16
__global__ __launch_bounds__(256) void build_wsw(
    const void* __restrict__ W_ih, const void* __restrict__ W_hh,
    bf16* __restrict__ Wsw, const int* __restrict__ meta)
{
  const int isf = meta[0];
  int idx = blockIdx.x * 256 + threadIdx.x;   // over 2*8*32*5*64 = 163840
  if (idx >= 2 * NSL * NKB * NF * 64) return;
  const int lane = idx & 63;
  const int f    = (idx >> 6) % NF;
  const int kb   = (idx / (64 * NF)) % NKB;
  const int sl   = (idx / (64 * NF * NKB)) % NSL;
  const int d    = idx / (64 * NF * NKB * NSL);
  const int n    = lane & 31;
  const int k0   = kb * 16 + (lane >> 5) * 8;
  const int g = (f < 4) ? (16 + f * H_ + sl * 32 + n) : ((n < 16) ? n : -1);
  short8 v;
  #pragma unroll
  for (int j = 0; j < 8; ++j) {
    float val = 0.f;
    const int k = k0 + j;
    if (g >= 0)
      val = (k < D_) ? ldF(W_ih, (size_t)g * D_ + (d ? (D_ - 1 - k) : k), isf)
                     : ldF(W_hh, (size_t)g * H_ + (k - D_), isf);
    v[j] = f2bs(val);
  }
  *(short8*)(Wsw + (size_t)idx * 8) = v;
}

// ---------------------------------------------------------------------------
// Persistent fused recurrence. Round-5 change: ZERO bulk cache maintenance.
//  - h exchange moved to agent-scope RELAXED atomic 8B loads/stores
//    (sc0 sc1: L1-bypassing, IC-coherent) -> no buffer_inv / buffer_wbl2
//    per step. xs / Wsw-f4 / bias stay L2-hot for the whole scan.
//  - hy store path: wave-local LDS 32x32 transpose tile -> A-frag image ->
//    4x 8B atomic stores per lane (was 1024 scalar 2B scattered stores).
//  - reader prefetches all 16 h-chunks (32x 8B atomic loads) into regs,
//    then runs the hs GEMM half from registers.
//  - counter protocol unchanged (padded slots, relaxed poll, relaxed add;
//    ordering: stores drained by the pre-signal barrier's vmcnt(0)).
// ---------------------------------------------------------------------------
__global__ __launch_bounds__(256, 1) void onlstm_persist(
    const short* __restrict__ xs, const short* __restrict__ Wsw,
    short* __restrict__ hs, float* __restrict__ cs,
    const float* __restrict__ bsum, void* __restrict__ out,
    const int* __restrict__ meta, int* __restrict__ ctr,
    int b_lo, int b_hi)
{
  __shared__ short Wl[NKB * 4 * 512];          // 128 KiB: frags f0..3
  __shared__ __align__(16) short Ht[NMB][32][40];  // 10 KiB: per-wave hy transpose

  const int tid  = threadIdx.x;
  const int lane = tid & 63;
  const int w    = tid >> 6;            // wave = mblock

  // XCD-grouped: group (rb,d) siblings (s=0..7) share lin%8 -> same XCD.
  const int lin = blockIdx.x;
  const int rb  = (lin & 7) + 8 * ((lin >> 3) >> 4);
  const int p   = (lin >> 3) & 15;
  const int d   = p >> 3;
  const int s   = p & 7;

  const int col   = lane & 31;
  const int khalf = lane >> 5;
  const int isf   = meta[0];

  const short* wsrc = Wsw + ((size_t)(d * NSL + s) * NKB) * (NF * 512);

  // ---- one-time: stage f0..3 frags into LDS (coalesced 16B/lane) ----
  for (int i = tid; i < NKB * 4 * 64; i += 256) {
    const int kb = i >> 8, rem = i & 255, f = rem >> 6, l = rem & 63;
    *(short8*)&Wl[((kb * 4 + f) << 9) + (l << 3)] =
        *(const short8*)(wsrc + ((kb * 5 + f) << 9) + (l << 3));
  }
  __syncthreads();

  // bias preloads (L1/L2 hits)
  float bg[4];
  #pragma unroll
  for (int f = 0; f < 4; ++f) bg[f] = bsum[16 + f * H_ + s * 32 + col];
  const float c0b = (col < 16) ? bsum[col] : 0.f;

  // epilogue addressing for e = s*32+col
  const int e = s * 32 + col;

  int* gctr = ctr + (size_t)(d * NRB + rb) * CTRSTRIDE;  // private cacheline
  const short* w4p = wsrc + 4 * 512 + lane * 8;   // f4 frag, stride 5*512/chunk

  float* csP = cs + (((size_t)(d * NSL + s) * NRB + rb) * NMB + w) * 1024 + lane;

  f32x16 creg;                                    // c carry: registers
  if (b_lo > 0) {
    #pragma unroll
    for (int r = 0; r < 16; ++r) creg[r] = csP[r * 64];
  } else {
    #pragma unroll
    for (int r = 0; r < 16; ++r) creg[r] = 0.f;
  }

  for (int b = b_lo; b < b_hi; ++b) {
    const int len_s  = meta[8 + b];
    const int base_s = meta[40 + b];

    f32x16 acc[NF];
    #pragma unroll
    for (int f = 0; f < NF; ++f)
      #pragma unroll
      for (int r = 0; r < 16; ++r) acc[f][r] = 0.f;

    // ---- xs half (K chunks 0..15): A + f4 pipelined 3 deep from global,
    // f0..3 from LDS-resident W. Overlaps siblings' step b-1 tails. ----
    {
      const short* aPtr = xs + (((size_t)b * NRB + rb) * 16 * NMB + w) * 512 + lane * 8;
      const short* w4q  = w4p;
      short8 a0 = *(const short8*)(aPtr);
      short8 a1 = *(const short8*)(aPtr + 2048);
      short8 a2 = *(const short8*)(aPtr + 4096);
      short8 q0 = *(const short8*)(w4q);
      short8 q1 = *(const short8*)(w4q + 2560);
      short8 q2 = *(const short8*)(w4q + 5120);
      #pragma unroll
      for (int kb = 0; kb < 16; ++kb) {
        const short8 af = a0, b4 = q0;
        a0 = a1; a1 = a2; q0 = q1; q1 = q2;
        if (kb < 13) {
          a2 = *(const short8*)(aPtr + (kb + 3) * 2048);
          q2 = *(const short8*)(w4q + (kb + 3) * 2560);
        }
        #pragma unroll
        for (int f = 0; f < 4; ++f) {
          const short8 bfr = *(const short8*)&Wl[((kb * 4 + f) << 9) + (lane << 3)];
          acc[f] = __builtin_amdgcn_mfma_f32_32x32x16_bf16(af, bfr, acc[f], 0, 0, 0);
        }
        acc[4] = __builtin_amdgcn_mfma_f32_32x32x16_bf16(af, b4, acc[4], 0, 0, 0);
      }
    }

    // ---- wait for siblings' step b-1 signals, then hs half ----
    if (b) {
      if (tid == 0) {
        ull t0 = __builtin_amdgcn_s_memrealtime();
        while (__hip_atomic_load(gctr, __ATOMIC_RELAXED,
                                 __HIP_MEMORY_SCOPE_AGENT) < 8 * b) {
          __builtin_amdgcn_s_sleep(1);
          if (__builtin_amdgcn_s_memrealtime() - t0 > 40000000ull) break; // no hang
        }
      }
      __syncthreads();

      // prefetch all 16 h-chunks (parity (b&1)^1) via coherent 8B atomic loads
      ull hfA[16], hfB[16];
      {
        const short* hbase = hs + (((size_t)(((b & 1) ^ 1) * 2 + d) * NRB + rb) * 16 * NMB + w) * 512;
        #pragma unroll
        for (int kb = 0; kb < 16; ++kb) {
          const ull* p = (const ull*)(hbase + (size_t)kb * NMB * 512) + lane * 2;
          hfA[kb] = __hip_atomic_load(p,     __ATOMIC_RELAXED, __HIP_MEMORY_SCOPE_AGENT);
          hfB[kb] = __hip_atomic_load(p + 1, __ATOMIC_RELAXED, __HIP_MEMORY_SCOPE_AGENT);
        }
      }

      // hs half (K chunks 16..31): A from prefetched regs, f4 pipelined.
      const short* w4q = w4p + 16 * 2560;
      short8 q0 = *(const short8*)(w4q);
      short8 q1 = *(const short8*)(w4q + 2560);
      short8 q2 = *(const short8*)(w4q + 5120);
      #pragma unroll
      for (int kb = 0; kb < 16; ++kb) {
        union { ull u[2]; short8 v; } af;
        af.u[0] = hfA[kb]; af.u[1] = hfB[kb];
        const short8 b4 = q0;
        q0 = q1; q1 = q2;
        if (kb < 13) q2 = *(const short8*)(w4q + (kb + 3) * 2560);
        #pragma unroll
        for (int f = 0; f < 4; ++f) {
          const short8 bfr = *(const short8*)&Wl[(((16 + kb) * 4 + f) << 9) + (lane << 3)];
          acc[f] = __builtin_amdgcn_mfma_f32_32x32x16_bf16(af.v, bfr, acc[f], 0, 0, 0);
        }
        acc[4] = __builtin_amdgcn_mfma_f32_32x32x16_bf16(af.v, b4, acc[4], 0, 0, 0);
      }
    }
    // b==0: h is zero, hs half contributes nothing -> skipped entirely.

    // ---- epilogue ----
    // C layout: col = lane&31, row = (r&3) + 8*(r>>2) + 4*(lane>>5).
    // Stage-batched shuffle trees (16 parallel chains).
    f32x16 gv, mx, Sv, Pv;
    #pragma unroll
    for (int r = 0; r < 16; ++r) gv[r] = acc[4][r] + c0b;  // cols>=16: exactly 0
    #pragma unroll
    for (int r = 0; r < 16; ++r) mx[r] = gv[r];
    #pragma unroll
    for (int r = 0; r < 16; ++r) { float t = __shfl_xor(mx[r], 1); mx[r] = fmaxf(mx[r], t); }
    #pragma unroll
    for (int r = 0; r < 16; ++r) { float t = __shfl_xor(mx[r], 2); mx[r] = fmaxf(mx[r], t); }
    #pragma unroll
    for (int r = 0; r < 16; ++r) { float t = __shfl_xor(mx[r], 4); mx[r] = fmaxf(mx[r], t); }
    #pragma unroll
    for (int r = 0; r < 16; ++r) gv[r] = __expf(gv[r] - mx[r]);   // gv := ex
    const bool pin = (lane & 7) <= s;
    #pragma unroll
    for (int r = 0; r < 16; ++r) { Sv[r] = gv[r]; Pv[r] = pin ? gv[r] : 0.f; }
    #pragma unroll
    for (int r = 0; r < 16; ++r) { Sv[r] += __shfl_xor(Sv[r], 1); Pv[r] += __shfl_xor(Pv[r], 1); }
    #pragma unroll
    for (int r = 0; r < 16; ++r) { Sv[r] += __shfl_xor(Sv[r], 2); Pv[r] += __shfl_xor(Pv[r], 2); }
    #pragma unroll
    for (int r = 0; r < 16; ++r) { Sv[r] += __shfl_xor(Sv[r], 4); Pv[r] += __shfl_xor(Pv[r], 4); }
    #pragma unroll
    for (int r = 0; r < 16; ++r) Pv[r] = __fdividef(Pv[r], Sv[r]);  // Pv := ratio
    f32x16 cinv, cfgv;
    #pragma unroll
    for (int r = 0; r < 16; ++r) cinv[r] = 1.f - __shfl(Pv[r], khalf * 32);
    #pragma unroll
    for (int r = 0; r < 16; ++r) cfgv[r] = __shfl(Pv[r], khalf * 32 + 8);

    #pragma unroll
    for (int r = 0; r < 16; ++r) {
      const int row = (r & 3) + 8 * (r >> 2) + 4 * khalf;
      const float cin = cinv[r];
      const float cfg = cfgv[r];
      const float og = sigmoidf_(acc[0][r] + bg[0]);
      const float cg = tanh_   (acc[1][r] + bg[1]);
      const float ig = sigmoidf_(acc[2][r] + bg[2]);
      const float fg = sigmoidf_(acc[3][r] + bg[3]);
      const float ov = cfg * cin;
      const float f2 = fg * ov + (cfg - ov);
      const float i2 = ig * ov + (cin - ov);
      const float cy = f2 * creg[r] + i2 * cg;
      creg[r] = cy;
      const float hy = og * tanh_(cy);
      Ht[w][row][col] = f2bs(hy);         // wave-local transpose tile
      const int t = rb * 128 + w * 32 + row;
      if (t < len_s) {
        const size_t o = (size_t)(base_s + t) * (2 * H_) + (size_t)d * H_ + e;
        if (isf) ((float*)out)[o] = hy;
        else     ((bf16*)out)[o]  = __float2bfloat16(hy);
      }
    }

    // ---- hy -> A-frag image via coherent 8B atomic stores (4/lane) ----
    {
      const int m  = lane & 31;
      const int k8 = lane >> 5;
      short* hbase = hs + (((size_t)((b & 1) * 2 + d) * NRB + rb) * 16 * NMB + w) * 512;
      #pragma unroll
      for (int c = 0; c < 2; ++c) {
        ull lo = *(const ull*)&Ht[w][m][c * 16 + k8 * 8];
        ull hi = *(const ull*)&Ht[w][m][c * 16 + k8 * 8 + 4];
        ull* q = (ull*)(hbase + (size_t)(2 * s + c) * NMB * 512) + lane * 2;
        __hip_atomic_store(q,     lo, __ATOMIC_RELAXED, __HIP_MEMORY_SCOPE_AGENT);
        __hip_atomic_store(q + 1, hi, __ATOMIC_RELAXED, __HIP_MEMORY_SCOPE_AGENT);
      }
    }

    // ---- arrive: barrier drains all stores (vmcnt(0) before s_barrier),
    // then one RELAXED add signals; no cache maintenance anywhere. ----
    __syncthreads();
    if (tid == 0)
      __hip_atomic_fetch_add(gctr, 1, __ATOMIC_RELAXED, __HIP_MEMORY_SCOPE_AGENT);
  }

  if (b_hi < B_) {                 // per-step fallback mode: spill c carry
    #pragma unroll
    for (int r = 0; r < 16; ++r) csP[r * 64] = creg[r];
  }
}

// ---------------------------------------------------------------------------
extern "C" void kernel_launch(void* const* d_in, const int* in_sizes, int n_in,
                              void* d_out, int out_size, void* d_ws, size_t ws_size,
                              hipStream_t stream)
{
  const void* x    = d_in[0];
  const int*  sl   = (const int*)d_in[1];
  const void* W_ih = d_in[2];
  const void* b_ih = d_in[3];
  const void* W_hh = d_in[4];
  const void* b_hh = d_in[5];

  char* ws = (char*)d_ws;
  size_t off = 0;
  auto alloc = [&](size_t bytes) {
    void* p = ws + off;
    off = (off + bytes + 255) & ~(size_t)255;
    return p;
  };
  int*   meta = (int*)  alloc(128 * sizeof(int));
  short* xs   = (short*)alloc((size_t)B_ * T_ * D_ * sizeof(short));            // 32 MB
  short* Wsw  = (short*)alloc((size_t)2 * NSL * NKB * NF * 512 * sizeof(short)); // 2.6 MB
  short* hs   = (short*)alloc((size_t)2 * 2 * T_ * H_ * sizeof(short));         // 4 MB [parity][dir]
  float* bsum = (float*)alloc((size_t)G_ * sizeof(float));
  int*   ctr  = (int*)  alloc((size_t)32 * CTRSTRIDE * sizeof(int));            // padded: 1 line/group
  float* cs   = (float*)alloc((size_t)2 * NSL * NRB * NMB * 1024 * sizeof(float)); // 4 MB (fallback only)
  const bool have_cs = (off <= ws_size);

  hipMemsetAsync(hs, 0, (size_t)2 * 2 * T_ * H_ * sizeof(short), stream);
  hipMemsetAsync(ctr, 0, (size_t)32 * CTRSTRIDE * sizeof(int), stream);

  detect_prep<<<1, 256, 0, stream>>>((const unsigned short*)x, sl, meta);
  build_bsum<<<(G_ + 255) / 256, 256, 0, stream>>>(b_ih, b_hh, bsum, meta);
  build_xs<<<(int)(((size_t)B_ * T_ * D_ / 8 + 255) / 256), 256, 0, stream>>>(x, (bf16*)xs, meta);
  build_wsw<<<(2 * NSL * NKB * NF * 64 + 255) / 256, 256, 0, stream>>>(W_ih, W_hh, (bf16*)Wsw, meta);

  // Preferred: cooperative persistent launch (co-residency guaranteed).
  int b_lo = 0, b_hi = B_;
  void* args[] = {(void*)&xs, (void*)&Wsw, (void*)&hs, (void*)&cs, (void*)&bsum,
                  (void*)&d_out, (void*)&meta, (void*)&ctr, (void*)&b_lo, (void*)&b_hi};
  hipError_t ce = hipLaunchCooperativeKernel((const void*)onlstm_persist,
                                             dim3(256), dim3(256), args, 0, stream);
  if (ce != hipSuccess) {
    (void)hipGetLastError();   // clear error state
    if (have_cs) {
      // Fallback: per-step launches; inter-step sync = kernel boundary.
      for (int b = 0; b < B_; ++b)
        onlstm_persist<<<dim3(256), dim3(256), 0, stream>>>(
            xs, Wsw, hs, cs, bsum, d_out, meta, ctr, b, b + 1);
    } else {
      // Last resort: regular persistent launch (structural residency + timeout).
      onlstm_persist<<<dim3(256), dim3(256), 0, stream>>>(
          xs, Wsw, hs, cs, bsum, d_out, meta, ctr, 0, B_);
    }
  }
}

// Round 9
// 626.860 us; speedup vs baseline: 2.5435x; 1.0787x over previous
//
#include <hip/hip_runtime.h>
#include <hip/hip_bf16.h>

// B=32, T=2048, D=256, H=256, CS=32, N=8, G=4H+2N=1040.
// Scan over BATCH axis (32 steps), carry (T,H). Backward dir = col-reversed W_ih.
#define B_  32
#define T_  2048
#define D_  256
#define H_  256
#define G_  1040

#define NSL 8      // e-slices of width 32 (== CS; slice s == chunk n)
#define NRB 16     // row-blocks of 128 rows
#define NMB 4      // mblocks (1 per wave) of 32 rows
#define NKB 32     // K16 chunks over KK=512
#define NF  5      // B col-frags: og,cg,ig,fg (32 cols) + [cols 0..15 | zeros]
#define CTRSTRIDE 64   // ints per group counter slot (256 B)

using bf16   = __hip_bfloat16;
using short8 = __attribute__((ext_vector_type(8))) short;
using f32x16 = __attribute__((ext_vector_type(16))) float;
using ull    = unsigned long long;

__device__ inline float sigmoidf_(float v) {
  return __fdividef(1.f, 1.f + __expf(-v));
}
__device__ inline float tanh_(float v) {
  v = fminf(fmaxf(v, -15.f), 15.f);
  float e = __expf(2.f * v);
  return __fdividef(e - 1.f, e + 1.f);
}
__device__ inline float bf2f(unsigned short u) {
  union { unsigned int i; float f; } c; c.i = ((unsigned int)u) << 16; return c.f;
}
__device__ inline float ldF(const void* p, size_t i, int isf) {
  return isf ? ((const float*)p)[i] : bf2f(((const unsigned short*)p)[i]);
}
__device__ inline short f2bs(float v) {
  bf16 h = __float2bfloat16(v);
  return *(short*)&h;
}

// meta: [0]=is_fp32, [8+b]=seq_len[b], [40+b]=row base[b]
__global__ __launch_bounds__(256) void detect_prep(
    const unsigned short* __restrict__ xh, const int* __restrict__ sli,
    int* __restrict__ meta)
{
  __shared__ int s_bad;
  if (threadIdx.x == 0) s_bad = 0;
  __syncthreads();
  int bad = 0;
  for (int i = threadIdx.x; i < 1024; i += 256) {
    float f = bf2f(xh[i]);
    if (!(fabsf(f) < 100.f)) bad = 1;
  }
  if (bad) atomicOr(&s_bad, 1);
  __syncthreads();
  if (threadIdx.x == 0) {
    meta[0] = s_bad;
    bool is64 = true;
    for (int i = 1; i < 32; i += 2) if (sli[i] != 0) is64 = false;
    int base = 0;
    for (int b = 0; b < B_; ++b) {
      int v = is64 ? sli[2 * b] : sli[b];
      meta[8 + b]  = v;
      meta[40 + b] = base;
      base += v;
    }
  }
}

__global__ __launch_bounds__(256) void build_bsum(
    const void* __restrict__ b_ih, const void* __restrict__ b_hh,
    float* __restrict__ bsum, const int* __restrict__ meta)
{
  const int isf = meta[0];
  int i = blockIdx.x * 256 + threadIdx.x;
  if (i < G_) bsum[i] = ldF(b_ih, i, isf) + ldF(b_hh, i, isf);
}

// xs[b][rb(16)][kbx(16)][mb(4)][lane(64)][8]: A-frag image for 32x32x16.
// Round-9: VECTORIZED. bf16 path is an identity re-layout -> one 16B vector
// load + one 16B store (was 8 scalar load/convert round-trips). fp32 path:
// 8 consecutive float loads (compiler merges to 2x dwordx4) + convert.
__global__ __launch_bounds__(256) void build_xs(
    const void* __restrict__ x, bf16* __restrict__ xs,
    const int* __restrict__ meta)
{
  const int isf = meta[0];
  size_t idx = (size_t)blockIdx.x * 256 + threadIdx.x;   // over B*T*D/8
  if (idx >= (size_t)B_ * T_ * D_ / 8) return;
  const int b  = (int)(idx >> 16);     // T*D/8 = 65536 per batch
  const int r  = (int)(idx & 65535);
  const int t  = r >> 5;               // 0..2047
  const int kc = r & 31;               // 8-elem k-chunk; k0 = kc*8
  const size_t src = ((size_t)b * T_ + t) * D_ + kc * 8;
  short8 v;
  if (!isf) {
    v = *(const short8*)((const unsigned short*)x + src);   // 16B copy
  } else {
    const float* xf = (const float*)x + src;
    #pragma unroll
    for (int j = 0; j < 8; ++j) v[j] = f2bs(xf[j]);
  }
  const int rb = t >> 7, mb = (t >> 5) & 3, trow = t & 31;
  const int kbx = kc >> 1, k8 = kc & 1;
  const size_t off = ((((size_t)b * 16 + rb) * 16 + kbx) * 4 + mb) * 64
                     + (k8 * 32 + trow);
  *(short8*)(xs + off * 8) = v;
}

// Wsw[d][s][kb(32)][f(5)][lane(64)][8]: B-frag image for 32x32x16
__global__ __launch_bounds__(256) void build_wsw(
    const void* __restrict__ W_ih, const void* __restrict__ W_hh,
    bf16* __restrict__ Wsw, const int* __restrict__ meta)
{
  const int isf = meta[0];
  int idx = blockIdx.x * 256 + threadIdx.x;   // over 2*8*32*5*64 = 163840
  if (idx >= 2 * NSL * NKB * NF * 64) return;
  const int lane = idx & 63;
  const int f    = (idx >> 6) % NF;
  const int kb   = (idx / (64 * NF)) % NKB;
  const int sl   = (idx / (64 * NF * NKB)) % NSL;
  const int d    = idx / (64 * NF * NKB * NSL);
  const int n    = lane & 31;
  const int k0   = kb * 16 + (lane >> 5) * 8;
  const int g = (f < 4) ? (16 + f * H_ + sl * 32 + n) : ((n < 16) ? n : -1);
  short8 v;
  #pragma unroll
  for (int j = 0; j < 8; ++j) {
    float val = 0.f;
    const int k = k0 + j;
    if (g >= 0)
      val = (k < D_) ? ldF(W_ih, (size_t)g * D_ + (d ? (D_ - 1 - k) : k), isf)
                     : ldF(W_hh, (size_t)g * H_ + (k - D_), isf);
    v[j] = f2bs(val);
  }
  *(short8*)(Wsw + (size_t)idx * 8) = v;
}

// ---------------------------------------------------------------------------
// Persistent fused recurrence. Round-9: round-5 sync structure VERBATIM
// (block-barrier arrive + tid0 signal, 8*b threshold, inline out stores —
// the configuration that passed at 532us). Rounds 6-8's per-wave arrive
// failed 3x -> dropped. Only protocol-independent change kept: cross-step
// xs register prefetch (read-only data; next step's 16 A-chunks loaded into
// the same 64 VGPRs during this step's xs GEMM, completing under
// poll+hs+epilogue).
// ---------------------------------------------------------------------------
__global__ __launch_bounds__(256, 1) void onlstm_persist(
    const short* __restrict__ xs, const short* __restrict__ Wsw,
    short* __restrict__ hs, float* __restrict__ cs,
    const float* __restrict__ bsum, void* __restrict__ out,
    const int* __restrict__ meta, int* __restrict__ ctr,
    int b_lo, int b_hi)
{
  __shared__ short Wl[NKB * 4 * 512];          // 128 KiB: frags f0..3
  __shared__ __align__(16) short Ht[NMB][32][40];  // 10 KiB: per-wave hy transpose

  const int tid  = threadIdx.x;
  const int lane = tid & 63;
  const int w    = tid >> 6;            // wave = mblock

  // XCD-grouped: group (rb,d) siblings (s=0..7) share lin%8 -> same XCD.
  const int lin = blockIdx.x;
  const int rb  = (lin & 7) + 8 * ((lin >> 3) >> 4);
  const int p   = (lin >> 3) & 15;
  const int d   = p >> 3;
  const int s   = p & 7;

  const int col   = lane & 31;
  const int khalf = lane >> 5;
  const int isf   = meta[0];

  const short* wsrc = Wsw + ((size_t)(d * NSL + s) * NKB) * (NF * 512);

  // ---- one-time: stage f0..3 frags into LDS (coalesced 16B/lane) ----
  for (int i = tid; i < NKB * 4 * 64; i += 256) {
    const int kb = i >> 8, rem = i & 255, f = rem >> 6, l = rem & 63;
    *(short8*)&Wl[((kb * 4 + f) << 9) + (l << 3)] =
        *(const short8*)(wsrc + ((kb * 5 + f) << 9) + (l << 3));
  }
  __syncthreads();

  // bias preloads (L1/L2 hits)
  float bg[4];
  #pragma unroll
  for (int f = 0; f < 4; ++f) bg[f] = bsum[16 + f * H_ + s * 32 + col];
  const float c0b = (col < 16) ? bsum[col] : 0.f;

  // epilogue addressing for e = s*32+col
  const int e = s * 32 + col;

  int* gctr = ctr + (size_t)(d * NRB + rb) * CTRSTRIDE;  // private cacheline
  const short* w4p = wsrc + 4 * 512 + lane * 8;   // f4 frag, stride 5*512/chunk

  float* csP = cs + (((size_t)(d * NSL + s) * NRB + rb) * NMB + w) * 1024 + lane;

  f32x16 creg;                                    // c carry: registers
  if (b_lo > 0) {
    #pragma unroll
    for (int r = 0; r < 16; ++r) creg[r] = csP[r * 64];
  } else {
    #pragma unroll
    for (int r = 0; r < 16; ++r) creg[r] = 0.f;
  }

  // prologue: synchronously prefetch step b_lo's xs chunks into registers
  short8 xn[16];
  {
    const short* aPtr = xs + (((size_t)b_lo * NRB + rb) * 16 * NMB + w) * 512 + lane * 8;
    #pragma unroll
    for (int kb = 0; kb < 16; ++kb)
      xn[kb] = *(const short8*)(aPtr + (size_t)kb * 2048);
  }

  for (int b = b_lo; b < b_hi; ++b) {
    const int len_s  = meta[8 + b];
    const int base_s = meta[40 + b];

    f32x16 acc[NF];
    #pragma unroll
    for (int f = 0; f < NF; ++f)
      #pragma unroll
      for (int r = 0; r < 16; ++r) acc[f][r] = 0.f;

    // ---- xs half (K chunks 0..15): A from registers; prefetch next step's
    // chunk into the same register right after consumption. f0..3 from LDS,
    // f4 pipelined 3-deep from global (L2-hot). ----
    {
      const short* aNext = xs + (((size_t)(b + 1) * NRB + rb) * 16 * NMB + w) * 512 + lane * 8;
      const bool pf = (b + 1 < b_hi);
      const short* w4q = w4p;
      short8 q0 = *(const short8*)(w4q);
      short8 q1 = *(const short8*)(w4q + 2560);
      short8 q2 = *(const short8*)(w4q + 5120);
      #pragma unroll
      for (int kb = 0; kb < 16; ++kb) {
        const short8 af = xn[kb];
        if (pf) xn[kb] = *(const short8*)(aNext + (size_t)kb * 2048);  // next-step prefetch
        const short8 b4 = q0;
        q0 = q1; q1 = q2;
        if (kb < 13) q2 = *(const short8*)(w4q + (kb + 3) * 2560);
        #pragma unroll
        for (int f = 0; f < 4; ++f) {
          const short8 bfr = *(const short8*)&Wl[((kb * 4 + f) << 9) + (lane << 3)];
          acc[f] = __builtin_amdgcn_mfma_f32_32x32x16_bf16(af, bfr, acc[f], 0, 0, 0);
        }
        acc[4] = __builtin_amdgcn_mfma_f32_32x32x16_bf16(af, b4, acc[4], 0, 0, 0);
      }
    }

    // ---- wait: tid0 polls (8 sibling blocks signaled step b-1), then
    // __syncthreads releases the block (round-5 proven read side). ----
    if (b) {
      if (tid == 0) {
        ull t0 = __builtin_amdgcn_s_memrealtime();
        while (__hip_atomic_load(gctr, __ATOMIC_RELAXED,
                                 __HIP_MEMORY_SCOPE_AGENT) < 8 * b) {
          __builtin_amdgcn_s_sleep(1);
          if (__builtin_amdgcn_s_memrealtime() - t0 > 40000000ull) break; // no hang
        }
      }
      __syncthreads();

      // prefetch all 16 h-chunks (parity (b&1)^1) via coherent 8B atomic loads
      ull hfA[16], hfB[16];
      {
        const short* hbase = hs + (((size_t)(((b & 1) ^ 1) * 2 + d) * NRB + rb) * 16 * NMB + w) * 512;
        #pragma unroll
        for (int kb = 0; kb < 16; ++kb) {
          const ull* hp = (const ull*)(hbase + (size_t)kb * NMB * 512) + lane * 2;
          hfA[kb] = __hip_atomic_load(hp,     __ATOMIC_RELAXED, __HIP_MEMORY_SCOPE_AGENT);
          hfB[kb] = __hip_atomic_load(hp + 1, __ATOMIC_RELAXED, __HIP_MEMORY_SCOPE_AGENT);
        }
      }

      // hs half (K chunks 16..31): A from prefetched regs, f4 pipelined.
      const short* w4q = w4p + 16 * 2560;
      short8 q0 = *(const short8*)(w4q);
      short8 q1 = *(const short8*)(w4q + 2560);
      short8 q2 = *(const short8*)(w4q + 5120);
      #pragma unroll
      for (int kb = 0; kb < 16; ++kb) {
        union { ull u[2]; short8 v; } af;
        af.u[0] = hfA[kb]; af.u[1] = hfB[kb];
        const short8 b4 = q0;
        q0 = q1; q1 = q2;
        if (kb < 13) q2 = *(const short8*)(w4q + (kb + 3) * 2560);
        #pragma unroll
        for (int f = 0; f < 4; ++f) {
          const short8 bfr = *(const short8*)&Wl[(((16 + kb) * 4 + f) << 9) + (lane << 3)];
          acc[f] = __builtin_amdgcn_mfma_f32_32x32x16_bf16(af.v, bfr, acc[f], 0, 0, 0);
        }
        acc[4] = __builtin_amdgcn_mfma_f32_32x32x16_bf16(af.v, b4, acc[4], 0, 0, 0);
      }
    }
    // b==0: h is zero, hs half contributes nothing -> skipped entirely.

    // ---- epilogue ----
    // C layout: col = lane&31, row = (r&3) + 8*(r>>2) + 4*(lane>>5).
    // Stage-batched shuffle trees (16 parallel chains).
    f32x16 gv, mx, Sv, Pv;
    #pragma unroll
    for (int r = 0; r < 16; ++r) gv[r] = acc[4][r] + c0b;  // cols>=16: exactly 0
    #pragma unroll
    for (int r = 0; r < 16; ++r) mx[r] = gv[r];
    #pragma unroll
    for (int r = 0; r < 16; ++r) { float t = __shfl_xor(mx[r], 1); mx[r] = fmaxf(mx[r], t); }
    #pragma unroll
    for (int r = 0; r < 16; ++r) { float t = __shfl_xor(mx[r], 2); mx[r] = fmaxf(mx[r], t); }
    #pragma unroll
    for (int r = 0; r < 16; ++r) { float t = __shfl_xor(mx[r], 4); mx[r] = fmaxf(mx[r], t); }
    #pragma unroll
    for (int r = 0; r < 16; ++r) gv[r] = __expf(gv[r] - mx[r]);   // gv := ex
    const bool pin = (lane & 7) <= s;
    #pragma unroll
    for (int r = 0; r < 16; ++r) { Sv[r] = gv[r]; Pv[r] = pin ? gv[r] : 0.f; }
    #pragma unroll
    for (int r = 0; r < 16; ++r) { Sv[r] += __shfl_xor(Sv[r], 1); Pv[r] += __shfl_xor(Pv[r], 1); }
    #pragma unroll
    for (int r = 0; r < 16; ++r) { Sv[r] += __shfl_xor(Sv[r], 2); Pv[r] += __shfl_xor(Pv[r], 2); }
    #pragma unroll
    for (int r = 0; r < 16; ++r) { Sv[r] += __shfl_xor(Sv[r], 4); Pv[r] += __shfl_xor(Pv[r], 4); }
    #pragma unroll
    for (int r = 0; r < 16; ++r) Pv[r] = __fdividef(Pv[r], Sv[r]);  // Pv := ratio
    f32x16 cinv, cfgv;
    #pragma unroll
    for (int r = 0; r < 16; ++r) cinv[r] = 1.f - __shfl(Pv[r], khalf * 32);
    #pragma unroll
    for (int r = 0; r < 16; ++r) cfgv[r] = __shfl(Pv[r], khalf * 32 + 8);

    #pragma unroll
    for (int r = 0; r < 16; ++r) {
      const int row = (r & 3) + 8 * (r >> 2) + 4 * khalf;
      const float cin = cinv[r];
      const float cfg = cfgv[r];
      const float og = sigmoidf_(acc[0][r] + bg[0]);
      const float cg = tanh_   (acc[1][r] + bg[1]);
      const float ig = sigmoidf_(acc[2][r] + bg[2]);
      const float fg = sigmoidf_(acc[3][r] + bg[3]);
      const float ov = cfg * cin;
      const float f2 = fg * ov + (cfg - ov);
      const float i2 = ig * ov + (cin - ov);
      const float cy = f2 * creg[r] + i2 * cg;
      creg[r] = cy;
      const float hy = og * tanh_(cy);
      Ht[w][row][col] = f2bs(hy);         // wave-private transpose tile
      const int t = rb * 128 + w * 32 + row;
      if (t < len_s) {
        const size_t o = (size_t)(base_s + t) * (2 * H_) + (size_t)d * H_ + e;
        if (isf) ((float*)out)[o] = hy;
        else     ((bf16*)out)[o]  = __float2bfloat16(hy);
      }
    }

    // ---- hy -> A-frag image via coherent 8B atomic stores (4/lane) ----
    {
      const int m  = lane & 31;
      const int k8 = lane >> 5;
      short* hbase = hs + (((size_t)((b & 1) * 2 + d) * NRB + rb) * 16 * NMB + w) * 512;
      #pragma unroll
      for (int c = 0; c < 2; ++c) {
        ull lo = *(const ull*)&Ht[w][m][c * 16 + k8 * 8];
        ull hi = *(const ull*)&Ht[w][m][c * 16 + k8 * 8 + 4];
        ull* q = (ull*)(hbase + (size_t)(2 * s + c) * NMB * 512) + lane * 2;
        __hip_atomic_store(q,     lo, __ATOMIC_RELAXED, __HIP_MEMORY_SCOPE_AGENT);
        __hip_atomic_store(q + 1, hi, __ATOMIC_RELAXED, __HIP_MEMORY_SCOPE_AGENT);
      }
    }

    // ---- arrive: barrier drains all stores (vmcnt(0) before s_barrier),
    // then one RELAXED add signals (round-5 proven write side). ----
    __syncthreads();
    if (tid == 0)
      __hip_atomic_fetch_add(gctr, 1, __ATOMIC_RELAXED, __HIP_MEMORY_SCOPE_AGENT);
  }

  if (b_hi < B_) {                 // per-step fallback mode: spill c carry
    #pragma unroll
    for (int r = 0; r < 16; ++r) csP[r * 64] = creg[r];
  }
}

// ---------------------------------------------------------------------------
extern "C" void kernel_launch(void* const* d_in, const int* in_sizes, int n_in,
                              void* d_out, int out_size, void* d_ws, size_t ws_size,
                              hipStream_t stream)
{
  const void* x    = d_in[0];
  const int*  sl   = (const int*)d_in[1];
  const void* W_ih = d_in[2];
  const void* b_ih = d_in[3];
  const void* W_hh = d_in[4];
  const void* b_hh = d_in[5];

  char* ws = (char*)d_ws;
  size_t off = 0;
  auto alloc = [&](size_t bytes) {
    void* p = ws + off;
    off = (off + bytes + 255) & ~(size_t)255;
    return p;
  };
  int*   meta = (int*)  alloc(128 * sizeof(int));
  short* xs   = (short*)alloc((size_t)B_ * T_ * D_ * sizeof(short));            // 32 MB
  short* Wsw  = (short*)alloc((size_t)2 * NSL * NKB * NF * 512 * sizeof(short)); // 2.6 MB
  short* hs   = (short*)alloc((size_t)2 * 2 * T_ * H_ * sizeof(short));         // 4 MB [parity][dir]
  float* bsum = (float*)alloc((size_t)G_ * sizeof(float));
  int*   ctr  = (int*)  alloc((size_t)32 * CTRSTRIDE * sizeof(int));            // padded: 1 line/group
  float* cs   = (float*)alloc((size_t)2 * NSL * NRB * NMB * 1024 * sizeof(float)); // 4 MB (fallback only)
  const bool have_cs = (off <= ws_size);

  hipMemsetAsync(hs, 0, (size_t)2 * 2 * T_ * H_ * sizeof(short), stream);
  hipMemsetAsync(ctr, 0, (size_t)32 * CTRSTRIDE * sizeof(int), stream);

  detect_prep<<<1, 256, 0, stream>>>((const unsigned short*)x, sl, meta);
  build_bsum<<<(G_ + 255) / 256, 256, 0, stream>>>(b_ih, b_hh, bsum, meta);
  build_xs<<<(int)(((size_t)B_ * T_ * D_ / 8 + 255) / 256), 256, 0, stream>>>(x, (bf16*)xs, meta);
  build_wsw<<<(2 * NSL * NKB * NF * 64 + 255) / 256, 256, 0, stream>>>(W_ih, W_hh, (bf16*)Wsw, meta);

  // Preferred: cooperative persistent launch (co-residency guaranteed).
  int b_lo = 0, b_hi = B_;
  void* args[] = {(void*)&xs, (void*)&Wsw, (void*)&hs, (void*)&cs, (void*)&bsum,
                  (void*)&d_out, (void*)&meta, (void*)&ctr, (void*)&b_lo, (void*)&b_hi};
  hipError_t ce = hipLaunchCooperativeKernel((const void*)onlstm_persist,
                                             dim3(256), dim3(256), args, 0, stream);
  if (ce != hipSuccess) {
    (void)hipGetLastError();   // clear error state
    if (have_cs) {
      // Fallback: per-step launches; inter-step sync = kernel boundary.
      // Counter accumulates 8/group/launch, matching the 8*b thresholds.
      for (int b = 0; b < B_; ++b)
        onlstm_persist<<<dim3(256), dim3(256), 0, stream>>>(
            xs, Wsw, hs, cs, bsum, d_out, meta, ctr, b, b + 1);
    } else {
      // Last resort: regular persistent launch (structural residency + timeout).
      onlstm_persist<<<dim3(256), dim3(256), 0, stream>>>(
          xs, Wsw, hs, cs, bsum, d_out, meta, ctr, 0, B_);
    }
  }
}

// Round 11
// 616.450 us; speedup vs baseline: 2.5865x; 1.0169x over previous
//
#include <hip/hip_runtime.h>
#include <hip/hip_bf16.h>

// B=32, T=2048, D=256, H=256, CS=32, N=8, G=4H+2N=1040.
// Scan over BATCH axis (32 steps), carry (T,H). Backward dir = col-reversed W_ih.
#define B_  32
#define T_  2048
#define D_  256
#define H_  256
#define G_  1040

#define NSL 8      // e-slices of width 32 (== CS; slice s == chunk n)
#define NRB 16     // row-blocks of 128 rows
#define NMB 4      // mblocks (1 per wave) of 32 rows
#define NKB 32     // K16 chunks over KK=512
#define NF  5      // B col-frags: og,cg,ig,fg (32 cols) + [cols 0..15 | zeros]
#define CTRSTRIDE 64   // ints per group counter slot (256 B)

using bf16   = __hip_bfloat16;
using short8 = __attribute__((ext_vector_type(8))) short;
using f32x16 = __attribute__((ext_vector_type(16))) float;
using ull    = unsigned long long;

__device__ inline float sigmoidf_(float v) {
  return __fdividef(1.f, 1.f + __expf(-v));
}
__device__ inline float tanh_(float v) {
  v = fminf(fmaxf(v, -15.f), 15.f);
  float e = __expf(2.f * v);
  return __fdividef(e - 1.f, e + 1.f);
}
__device__ inline float bf2f(unsigned short u) {
  union { unsigned int i; float f; } c; c.i = ((unsigned int)u) << 16; return c.f;
}
__device__ inline float ldF(const void* p, size_t i, int isf) {
  return isf ? ((const float*)p)[i] : bf2f(((const unsigned short*)p)[i]);
}
__device__ inline short f2bs(float v) {
  bf16 h = __float2bfloat16(v);
  return *(short*)&h;
}

// meta: [0]=is_fp32, [8+b]=seq_len[b], [40+b]=row base[b]
__global__ __launch_bounds__(256) void detect_prep(
    const unsigned short* __restrict__ xh, const int* __restrict__ sli,
    int* __restrict__ meta)
{
  __shared__ int s_bad;
  if (threadIdx.x == 0) s_bad = 0;
  __syncthreads();
  int bad = 0;
  for (int i = threadIdx.x; i < 1024; i += 256) {
    float f = bf2f(xh[i]);
    if (!(fabsf(f) < 100.f)) bad = 1;
  }
  if (bad) atomicOr(&s_bad, 1);
  __syncthreads();
  if (threadIdx.x == 0) {
    meta[0] = s_bad;
    bool is64 = true;
    for (int i = 1; i < 32; i += 2) if (sli[i] != 0) is64 = false;
    int base = 0;
    for (int b = 0; b < B_; ++b) {
      int v = is64 ? sli[2 * b] : sli[b];
      meta[8 + b]  = v;
      meta[40 + b] = base;
      base += v;
    }
  }
}

__global__ __launch_bounds__(256) void build_bsum(
    const void* __restrict__ b_ih, const void* __restrict__ b_hh,
    float* __restrict__ bsum, const int* __restrict__ meta)
{
  const int isf = meta[0];
  int i = blockIdx.x * 256 + threadIdx.x;
  if (i < G_) bsum[i] = ldF(b_ih, i, isf) + ldF(b_hh, i, isf);
}

// xs[b][rb(16)][kbx(16)][mb(4)][lane(64)][8]: A-frag image for 32x32x16.
// Vectorized: bf16 path = one 16B copy; fp32 path = 8 mergeable loads.
__global__ __launch_bounds__(256) void build_xs(
    const void* __restrict__ x, bf16* __restrict__ xs,
    const int* __restrict__ meta)
{
  const int isf = meta[0];
  size_t idx = (size_t)blockIdx.x * 256 + threadIdx.x;   // over B*T*D/8
  if (idx >= (size_t)B_ * T_ * D_ / 8) return;
  const int b  = (int)(idx >> 16);     // T*D/8 = 65536 per batch
  const int r  = (int)(idx & 65535);
  const int t  = r >> 5;               // 0..2047
  const int kc = r & 31;               // 8-elem k-chunk; k0 = kc*8
  const size_t src = ((size_t)b * T_ + t) * D_ + kc * 8;
  short8 v;
  if (!isf) {
    v = *(const short8*)((const unsigned short*)x + src);   // 16B copy
  } else {
    const float* xf = (const float*)x + src;
    #pragma unroll
    for (int j = 0; j < 8; ++j) v[j] = f2bs(xf[j]);
  }
  const int rb = t >> 7, mb = (t >> 5) & 3, trow = t & 31;
  const int kbx = kc >> 1, k8 = kc & 1;
  const size_t off = ((((size_t)b * 16 + rb) * 16 + kbx) * 4 + mb) * 64
                     + (k8 * 32 + trow);
  *(short8*)(xs + off * 8) = v;
}

// Wsw[d][s][kb(32)][f(5)][lane(64)][8]: B-frag image for 32x32x16
__global__ __launch_bounds__(256) void build_wsw(
    const void* __restrict__ W_ih, const void* __restrict__ W_hh,
    bf16* __restrict__ Wsw, const int* __restrict__ meta)
{
  const int isf = meta[0];
  int idx = blockIdx.x * 256 + threadIdx.x;   // over 2*8*32*5*64 = 163840
  if (idx >= 2 * NSL * NKB * NF * 64) return;
  const int lane = idx & 63;
  const int f    = (idx >> 6) % NF;
  const int kb   = (idx / (64 * NF)) % NKB;
  const int sl   = (idx / (64 * NF * NKB)) % NSL;
  const int d    = idx / (64 * NF * NKB * NSL);
  const int n    = lane & 31;
  const int k0   = kb * 16 + (lane >> 5) * 8;
  const int g = (f < 4) ? (16 + f * H_ + sl * 32 + n) : ((n < 16) ? n : -1);
  short8 v;
  #pragma unroll
  for (int j = 0; j < 8; ++j) {
    float val = 0.f;
    const int k = k0 + j;
    if (g >= 0)
      val = (k < D_) ? ldF(W_ih, (size_t)g * D_ + (d ? (D_ - 1 - k) : k), isf)
                     : ldF(W_hh, (size_t)g * H_ + (k - D_), isf);
    v[j] = f2bs(val);
  }
  *(short8*)(Wsw + (size_t)idx * 8) = v;
}

// ---------------------------------------------------------------------------
// Persistent fused recurrence. Round-11 = round-9 (PASSING, 512us) with ONE
// change: out stores vectorized IN PLACE (still before the arrive barrier —
// the empirical rule from R6/7/8/10 is that stores must not move past the
// signal). The epilogue's Ht[w] tile is read back as 2 lanes/row x 16
// contiguous elements (2x16B) instead of 16 scalar 2B scattered stores + 16
// addr/branch chains per lane. The cross-lane in-wave Ht read is the SAME
// pattern as the adjacent hy->hs block (proven R5/R9). Sync untouched.
// ---------------------------------------------------------------------------
__global__ __launch_bounds__(256, 1) void onlstm_persist(
    const short* __restrict__ xs, const short* __restrict__ Wsw,
    short* __restrict__ hs, float* __restrict__ cs,
    const float* __restrict__ bsum, void* __restrict__ out,
    const int* __restrict__ meta, int* __restrict__ ctr,
    int b_lo, int b_hi)
{
  __shared__ short Wl[NKB * 4 * 512];          // 128 KiB: frags f0..3
  __shared__ __align__(16) short Ht[NMB][32][40];  // 10 KiB: per-wave hy transpose

  const int tid  = threadIdx.x;
  const int lane = tid & 63;
  const int w    = tid >> 6;            // wave = mblock

  // XCD-grouped: group (rb,d) siblings (s=0..7) share lin%8 -> same XCD.
  const int lin = blockIdx.x;
  const int rb  = (lin & 7) + 8 * ((lin >> 3) >> 4);
  const int p   = (lin >> 3) & 15;
  const int d   = p >> 3;
  const int s   = p & 7;

  const int col   = lane & 31;
  const int khalf = lane >> 5;
  const int isf   = meta[0];

  const short* wsrc = Wsw + ((size_t)(d * NSL + s) * NKB) * (NF * 512);

  // ---- one-time: stage f0..3 frags into LDS (coalesced 16B/lane) ----
  for (int i = tid; i < NKB * 4 * 64; i += 256) {
    const int kb = i >> 8, rem = i & 255, f = rem >> 6, l = rem & 63;
    *(short8*)&Wl[((kb * 4 + f) << 9) + (l << 3)] =
        *(const short8*)(wsrc + ((kb * 5 + f) << 9) + (l << 3));
  }
  __syncthreads();

  // bias preloads (L1/L2 hits)
  float bg[4];
  #pragma unroll
  for (int f = 0; f < 4; ++f) bg[f] = bsum[16 + f * H_ + s * 32 + col];
  const float c0b = (col < 16) ? bsum[col] : 0.f;

  int* gctr = ctr + (size_t)(d * NRB + rb) * CTRSTRIDE;  // private cacheline
  const short* w4p = wsrc + 4 * 512 + lane * 8;   // f4 frag, stride 5*512/chunk

  float* csP = cs + (((size_t)(d * NSL + s) * NRB + rb) * NMB + w) * 1024 + lane;

  f32x16 creg;                                    // c carry: registers
  if (b_lo > 0) {
    #pragma unroll
    for (int r = 0; r < 16; ++r) creg[r] = csP[r * 64];
  } else {
    #pragma unroll
    for (int r = 0; r < 16; ++r) creg[r] = 0.f;
  }

  // prologue: synchronously prefetch step b_lo's xs chunks into registers
  short8 xn[16];
  {
    const short* aPtr = xs + (((size_t)b_lo * NRB + rb) * 16 * NMB + w) * 512 + lane * 8;
    #pragma unroll
    for (int kb = 0; kb < 16; ++kb)
      xn[kb] = *(const short8*)(aPtr + (size_t)kb * 2048);
  }

  for (int b = b_lo; b < b_hi; ++b) {
    const int len_s  = meta[8 + b];
    const int base_s = meta[40 + b];

    f32x16 acc[NF];
    #pragma unroll
    for (int f = 0; f < NF; ++f)
      #pragma unroll
      for (int r = 0; r < 16; ++r) acc[f][r] = 0.f;

    // ---- xs half (K chunks 0..15): A from registers; prefetch next step's
    // chunk into the same register right after consumption. f0..3 from LDS,
    // f4 pipelined 3-deep from global (L2-hot). ----
    {
      const short* aNext = xs + (((size_t)(b + 1) * NRB + rb) * 16 * NMB + w) * 512 + lane * 8;
      const bool pf = (b + 1 < b_hi);
      const short* w4q = w4p;
      short8 q0 = *(const short8*)(w4q);
      short8 q1 = *(const short8*)(w4q + 2560);
      short8 q2 = *(const short8*)(w4q + 5120);
      #pragma unroll
      for (int kb = 0; kb < 16; ++kb) {
        const short8 af = xn[kb];
        if (pf) xn[kb] = *(const short8*)(aNext + (size_t)kb * 2048);  // next-step prefetch
        const short8 b4 = q0;
        q0 = q1; q1 = q2;
        if (kb < 13) q2 = *(const short8*)(w4q + (kb + 3) * 2560);
        #pragma unroll
        for (int f = 0; f < 4; ++f) {
          const short8 bfr = *(const short8*)&Wl[((kb * 4 + f) << 9) + (lane << 3)];
          acc[f] = __builtin_amdgcn_mfma_f32_32x32x16_bf16(af, bfr, acc[f], 0, 0, 0);
        }
        acc[4] = __builtin_amdgcn_mfma_f32_32x32x16_bf16(af, b4, acc[4], 0, 0, 0);
      }
    }

    // ---- wait: tid0 polls (8 sibling blocks signaled step b-1), then
    // __syncthreads releases the block (proven read side). ----
    if (b) {
      if (tid == 0) {
        ull t0 = __builtin_amdgcn_s_memrealtime();
        while (__hip_atomic_load(gctr, __ATOMIC_RELAXED,
                                 __HIP_MEMORY_SCOPE_AGENT) < 8 * b) {
          __builtin_amdgcn_s_sleep(1);
          if (__builtin_amdgcn_s_memrealtime() - t0 > 40000000ull) break; // no hang
        }
      }
      __syncthreads();

      // prefetch all 16 h-chunks (parity (b&1)^1) via coherent 8B atomic loads
      ull hfA[16], hfB[16];
      {
        const short* hbase = hs + (((size_t)(((b & 1) ^ 1) * 2 + d) * NRB + rb) * 16 * NMB + w) * 512;
        #pragma unroll
        for (int kb = 0; kb < 16; ++kb) {
          const ull* hp = (const ull*)(hbase + (size_t)kb * NMB * 512) + lane * 2;
          hfA[kb] = __hip_atomic_load(hp,     __ATOMIC_RELAXED, __HIP_MEMORY_SCOPE_AGENT);
          hfB[kb] = __hip_atomic_load(hp + 1, __ATOMIC_RELAXED, __HIP_MEMORY_SCOPE_AGENT);
        }
      }

      // hs half (K chunks 16..31): A from prefetched regs, f4 pipelined.
      const short* w4q = w4p + 16 * 2560;
      short8 q0 = *(const short8*)(w4q);
      short8 q1 = *(const short8*)(w4q + 2560);
      short8 q2 = *(const short8*)(w4q + 5120);
      #pragma unroll
      for (int kb = 0; kb < 16; ++kb) {
        union { ull u[2]; short8 v; } af;
        af.u[0] = hfA[kb]; af.u[1] = hfB[kb];
        const short8 b4 = q0;
        q0 = q1; q1 = q2;
        if (kb < 13) q2 = *(const short8*)(w4q + (kb + 3) * 2560);
        #pragma unroll
        for (int f = 0; f < 4; ++f) {
          const short8 bfr = *(const short8*)&Wl[(((16 + kb) * 4 + f) << 9) + (lane << 3)];
          acc[f] = __builtin_amdgcn_mfma_f32_32x32x16_bf16(af.v, bfr, acc[f], 0, 0, 0);
        }
        acc[4] = __builtin_amdgcn_mfma_f32_32x32x16_bf16(af.v, b4, acc[4], 0, 0, 0);
      }
    }
    // b==0: h is zero, hs half contributes nothing -> skipped entirely.

    // ---- epilogue ----
    // C layout: col = lane&31, row = (r&3) + 8*(r>>2) + 4*(lane>>5).
    // Stage-batched shuffle trees (16 parallel chains).
    f32x16 gv, mx, Sv, Pv;
    #pragma unroll
    for (int r = 0; r < 16; ++r) gv[r] = acc[4][r] + c0b;  // cols>=16: exactly 0
    #pragma unroll
    for (int r = 0; r < 16; ++r) mx[r] = gv[r];
    #pragma unroll
    for (int r = 0; r < 16; ++r) { float t = __shfl_xor(mx[r], 1); mx[r] = fmaxf(mx[r], t); }
    #pragma unroll
    for (int r = 0; r < 16; ++r) { float t = __shfl_xor(mx[r], 2); mx[r] = fmaxf(mx[r], t); }
    #pragma unroll
    for (int r = 0; r < 16; ++r) { float t = __shfl_xor(mx[r], 4); mx[r] = fmaxf(mx[r], t); }
    #pragma unroll
    for (int r = 0; r < 16; ++r) gv[r] = __expf(gv[r] - mx[r]);   // gv := ex
    const bool pin = (lane & 7) <= s;
    #pragma unroll
    for (int r = 0; r < 16; ++r) { Sv[r] = gv[r]; Pv[r] = pin ? gv[r] : 0.f; }
    #pragma unroll
    for (int r = 0; r < 16; ++r) { Sv[r] += __shfl_xor(Sv[r], 1); Pv[r] += __shfl_xor(Pv[r], 1); }
    #pragma unroll
    for (int r = 0; r < 16; ++r) { Sv[r] += __shfl_xor(Sv[r], 2); Pv[r] += __shfl_xor(Pv[r], 2); }
    #pragma unroll
    for (int r = 0; r < 16; ++r) { Sv[r] += __shfl_xor(Sv[r], 4); Pv[r] += __shfl_xor(Pv[r], 4); }
    #pragma unroll
    for (int r = 0; r < 16; ++r) Pv[r] = __fdividef(Pv[r], Sv[r]);  // Pv := ratio
    f32x16 cinv, cfgv;
    #pragma unroll
    for (int r = 0; r < 16; ++r) cinv[r] = 1.f - __shfl(Pv[r], khalf * 32);
    #pragma unroll
    for (int r = 0; r < 16; ++r) cfgv[r] = __shfl(Pv[r], khalf * 32 + 8);

    #pragma unroll
    for (int r = 0; r < 16; ++r) {
      const int row = (r & 3) + 8 * (r >> 2) + 4 * khalf;
      const float cin = cinv[r];
      const float cfg = cfgv[r];
      const float og = sigmoidf_(acc[0][r] + bg[0]);
      const float cg = tanh_   (acc[1][r] + bg[1]);
      const float ig = sigmoidf_(acc[2][r] + bg[2]);
      const float fg = sigmoidf_(acc[3][r] + bg[3]);
      const float ov = cfg * cin;
      const float f2 = fg * ov + (cfg - ov);
      const float i2 = ig * ov + (cin - ov);
      const float cy = f2 * creg[r] + i2 * cg;
      creg[r] = cy;
      const float hy = og * tanh_(cy);
      Ht[w][row][col] = f2bs(hy);         // wave-private transpose tile
    }

    // ---- vectorized out stores from Ht (IN the pre-barrier critical
    // section, same placement class as R9's scalar stores): 2 lanes/row,
    // each a contiguous 16-elem run. In-wave cross-lane Ht read — same
    // pattern as the hy->hs block below (proven R5/R9). ----
    {
      const int orow = lane >> 1;
      const int half = lane & 1;
      const int t = rb * 128 + w * 32 + orow;
      if (t < len_s) {
        const short* hsrc = &Ht[w][orow][half * 16];
        const size_t o = (size_t)(base_s + t) * (2 * H_) + (size_t)d * H_
                         + s * 32 + half * 16;
        short8 v0 = *(const short8*)(hsrc);
        short8 v1 = *(const short8*)(hsrc + 8);
        if (isf) {
          float* op = (float*)out + o;
          #pragma unroll
          for (int j = 0; j < 8; ++j) op[j]     = bf2f((unsigned short)v0[j]);
          #pragma unroll
          for (int j = 0; j < 8; ++j) op[8 + j] = bf2f((unsigned short)v1[j]);
        } else {
          short* op = (short*)out + o;
          *(short8*)(op)     = v0;
          *(short8*)(op + 8) = v1;
        }
      }
    }

    // ---- hy -> A-frag image via coherent 8B atomic stores (4/lane) ----
    {
      const int m  = lane & 31;
      const int k8 = lane >> 5;
      short* hbase = hs + (((size_t)((b & 1) * 2 + d) * NRB + rb) * 16 * NMB + w) * 512;
      #pragma unroll
      for (int c = 0; c < 2; ++c) {
        ull lo = *(const ull*)&Ht[w][m][c * 16 + k8 * 8];
        ull hi = *(const ull*)&Ht[w][m][c * 16 + k8 * 8 + 4];
        ull* q = (ull*)(hbase + (size_t)(2 * s + c) * NMB * 512) + lane * 2;
        __hip_atomic_store(q,     lo, __ATOMIC_RELAXED, __HIP_MEMORY_SCOPE_AGENT);
        __hip_atomic_store(q + 1, hi, __ATOMIC_RELAXED, __HIP_MEMORY_SCOPE_AGENT);
      }
    }

    // ---- arrive: barrier drains all stores (vmcnt(0) before s_barrier),
    // then one RELAXED add signals (proven write side). ----
    __syncthreads();
    if (tid == 0)
      __hip_atomic_fetch_add(gctr, 1, __ATOMIC_RELAXED, __HIP_MEMORY_SCOPE_AGENT);
  }

  if (b_hi < B_) {                 // per-step fallback mode: spill c carry
    #pragma unroll
    for (int r = 0; r < 16; ++r) csP[r * 64] = creg[r];
  }
}

// ---------------------------------------------------------------------------
extern "C" void kernel_launch(void* const* d_in, const int* in_sizes, int n_in,
                              void* d_out, int out_size, void* d_ws, size_t ws_size,
                              hipStream_t stream)
{
  const void* x    = d_in[0];
  const int*  sl   = (const int*)d_in[1];
  const void* W_ih = d_in[2];
  const void* b_ih = d_in[3];
  const void* W_hh = d_in[4];
  const void* b_hh = d_in[5];

  char* ws = (char*)d_ws;
  size_t off = 0;
  auto alloc = [&](size_t bytes) {
    void* p = ws + off;
    off = (off + bytes + 255) & ~(size_t)255;
    return p;
  };
  int*   meta = (int*)  alloc(128 * sizeof(int));
  short* xs   = (short*)alloc((size_t)B_ * T_ * D_ * sizeof(short));            // 32 MB
  short* Wsw  = (short*)alloc((size_t)2 * NSL * NKB * NF * 512 * sizeof(short)); // 2.6 MB
  short* hs   = (short*)alloc((size_t)2 * 2 * T_ * H_ * sizeof(short));         // 4 MB [parity][dir]
  float* bsum = (float*)alloc((size_t)G_ * sizeof(float));
  int*   ctr  = (int*)  alloc((size_t)32 * CTRSTRIDE * sizeof(int));            // padded: 1 line/group
  float* cs   = (float*)alloc((size_t)2 * NSL * NRB * NMB * 1024 * sizeof(float)); // 4 MB (fallback only)
  const bool have_cs = (off <= ws_size);

  hipMemsetAsync(hs, 0, (size_t)2 * 2 * T_ * H_ * sizeof(short), stream);
  hipMemsetAsync(ctr, 0, (size_t)32 * CTRSTRIDE * sizeof(int), stream);

  detect_prep<<<1, 256, 0, stream>>>((const unsigned short*)x, sl, meta);
  build_bsum<<<(G_ + 255) / 256, 256, 0, stream>>>(b_ih, b_hh, bsum, meta);
  build_xs<<<(int)(((size_t)B_ * T_ * D_ / 8 + 255) / 256), 256, 0, stream>>>(x, (bf16*)xs, meta);
  build_wsw<<<(2 * NSL * NKB * NF * 64 + 255) / 256, 256, 0, stream>>>(W_ih, W_hh, (bf16*)Wsw, meta);

  // Preferred: cooperative persistent launch (co-residency guaranteed).
  int b_lo = 0, b_hi = B_;
  void* args[] = {(void*)&xs, (void*)&Wsw, (void*)&hs, (void*)&cs, (void*)&bsum,
                  (void*)&d_out, (void*)&meta, (void*)&ctr, (void*)&b_lo, (void*)&b_hi};
  hipError_t ce = hipLaunchCooperativeKernel((const void*)onlstm_persist,
                                             dim3(256), dim3(256), args, 0, stream);
  if (ce != hipSuccess) {
    (void)hipGetLastError();   // clear error state
    if (have_cs) {
      // Fallback: per-step launches; inter-step sync = kernel boundary.
      // Counter accumulates 8/group/launch, matching the 8*b thresholds.
      for (int b = 0; b < B_; ++b)
        onlstm_persist<<<dim3(256), dim3(256), 0, stream>>>(
            xs, Wsw, hs, cs, bsum, d_out, meta, ctr, b, b + 1);
    } else {
      // Last resort: regular persistent launch (structural residency + timeout).
      onlstm_persist<<<dim3(256), dim3(256), 0, stream>>>(
          xs, Wsw, hs, cs, bsum, d_out, meta, ctr, 0, B_);
    }
  }
}

// Round 12
// 601.019 us; speedup vs baseline: 2.6529x; 1.0257x over previous
//
#include <hip/hip_runtime.h>
#include <hip/hip_bf16.h>

// B=32, T=2048, D=256, H=256, CS=32, N=8, G=4H+2N=1040.
// Scan over BATCH axis (32 steps), carry (T,H). Backward dir = col-reversed W_ih.
#define B_  32
#define T_  2048
#define D_  256
#define H_  256
#define G_  1040

#define NSL 8      // e-slices of width 32 (== CS; slice s == chunk n)
#define NRB 16     // row-blocks of 128 rows
#define NMB 4      // mblocks (1 per wave) of 32 rows
#define NKB 32     // K16 chunks over KK=512
#define NF  5      // B col-frags: og,cg,ig,fg (32 cols) + [cols 0..15 | zeros]
#define CTRSTRIDE 64   // ints per group counter slot (256 B)

using bf16   = __hip_bfloat16;
using short8 = __attribute__((ext_vector_type(8))) short;
using f32x16 = __attribute__((ext_vector_type(16))) float;
using ull    = unsigned long long;

__device__ inline float sigmoidf_(float v) {
  return __fdividef(1.f, 1.f + __expf(-v));
}
__device__ inline float tanh_(float v) {
  v = fminf(fmaxf(v, -15.f), 15.f);
  float e = __expf(2.f * v);
  return __fdividef(e - 1.f, e + 1.f);
}
__device__ inline float bf2f(unsigned short u) {
  union { unsigned int i; float f; } c; c.i = ((unsigned int)u) << 16; return c.f;
}
__device__ inline float ldF(const void* p, size_t i, int isf) {
  return isf ? ((const float*)p)[i] : bf2f(((const unsigned short*)p)[i]);
}
__device__ inline short f2bs(float v) {
  bf16 h = __float2bfloat16(v);
  return *(short*)&h;
}

// meta: [0]=is_fp32, [8+b]=seq_len[b], [40+b]=row base[b]
__global__ __launch_bounds__(256) void detect_prep(
    const unsigned short* __restrict__ xh, const int* __restrict__ sli,
    int* __restrict__ meta)
{
  __shared__ int s_bad;
  if (threadIdx.x == 0) s_bad = 0;
  __syncthreads();
  int bad = 0;
  for (int i = threadIdx.x; i < 1024; i += 256) {
    float f = bf2f(xh[i]);
    if (!(fabsf(f) < 100.f)) bad = 1;
  }
  if (bad) atomicOr(&s_bad, 1);
  __syncthreads();
  if (threadIdx.x == 0) {
    meta[0] = s_bad;
    bool is64 = true;
    for (int i = 1; i < 32; i += 2) if (sli[i] != 0) is64 = false;
    int base = 0;
    for (int b = 0; b < B_; ++b) {
      int v = is64 ? sli[2 * b] : sli[b];
      meta[8 + b]  = v;
      meta[40 + b] = base;
      base += v;
    }
  }
}

__global__ __launch_bounds__(256) void build_bsum(
    const void* __restrict__ b_ih, const void* __restrict__ b_hh,
    float* __restrict__ bsum, const int* __restrict__ meta)
{
  const int isf = meta[0];
  int i = blockIdx.x * 256 + threadIdx.x;
  if (i < G_) bsum[i] = ldF(b_ih, i, isf) + ldF(b_hh, i, isf);
}

// xs[b][rb(16)][kbx(16)][mb(4)][lane(64)][8]: A-frag image for 32x32x16.
// Vectorized: bf16 path = one 16B copy; fp32 path = 8 mergeable loads.
__global__ __launch_bounds__(256) void build_xs(
    const void* __restrict__ x, bf16* __restrict__ xs,
    const int* __restrict__ meta)
{
  const int isf = meta[0];
  size_t idx = (size_t)blockIdx.x * 256 + threadIdx.x;   // over B*T*D/8
  if (idx >= (size_t)B_ * T_ * D_ / 8) return;
  const int b  = (int)(idx >> 16);     // T*D/8 = 65536 per batch
  const int r  = (int)(idx & 65535);
  const int t  = r >> 5;               // 0..2047
  const int kc = r & 31;               // 8-elem k-chunk; k0 = kc*8
  const size_t src = ((size_t)b * T_ + t) * D_ + kc * 8;
  short8 v;
  if (!isf) {
    v = *(const short8*)((const unsigned short*)x + src);   // 16B copy
  } else {
    const float* xf = (const float*)x + src;
    #pragma unroll
    for (int j = 0; j < 8; ++j) v[j] = f2bs(xf[j]);
  }
  const int rb = t >> 7, mb = (t >> 5) & 3, trow = t & 31;
  const int kbx = kc >> 1, k8 = kc & 1;
  const size_t off = ((((size_t)b * 16 + rb) * 16 + kbx) * 4 + mb) * 64
                     + (k8 * 32 + trow);
  *(short8*)(xs + off * 8) = v;
}

// Wsw[d][s][kb(32)][f(5)][lane(64)][8]: B-frag image for 32x32x16
__global__ __launch_bounds__(256) void build_wsw(
    const void* __restrict__ W_ih, const void* __restrict__ W_hh,
    bf16* __restrict__ Wsw, const int* __restrict__ meta)
{
  const int isf = meta[0];
  int idx = blockIdx.x * 256 + threadIdx.x;   // over 2*8*32*5*64 = 163840
  if (idx >= 2 * NSL * NKB * NF * 64) return;
  const int lane = idx & 63;
  const int f    = (idx >> 6) % NF;
  const int kb   = (idx / (64 * NF)) % NKB;
  const int sl   = (idx / (64 * NF * NKB)) % NSL;
  const int d    = idx / (64 * NF * NKB * NSL);
  const int n    = lane & 31;
  const int k0   = kb * 16 + (lane >> 5) * 8;
  const int g = (f < 4) ? (16 + f * H_ + sl * 32 + n) : ((n < 16) ? n : -1);
  short8 v;
  #pragma unroll
  for (int j = 0; j < 8; ++j) {
    float val = 0.f;
    const int k = k0 + j;
    if (g >= 0)
      val = (k < D_) ? ldF(W_ih, (size_t)g * D_ + (d ? (D_ - 1 - k) : k), isf)
                     : ldF(W_hh, (size_t)g * H_ + (k - D_), isf);
    v[j] = f2bs(val);
  }
  *(short8*)(Wsw + (size_t)idx * 8) = v;
}

// ---------------------------------------------------------------------------
// Persistent fused recurrence. Round-12 = round-9 (best passing, 512us)
// + LDS W-frag register DOUBLE-BUFFER:
//  - R11's vectorized out stores REVERTED (caused 138K LDS bank conflicts,
//    512->534us regression) -> back to R9's in-r-loop scalar stores.
//  - NEW: each GEMM half preloads chunk kb's 4 Wl frags into registers and
//    issues chunk kb+1's ds_read_b128s BEFORE chunk kb's MFMAs. At 1
//    wave/SIMD the ~120cyc LDS latency was fully exposed per chunk
//    (~2-3us/step); now it hides under the MFMA+global-prefetch issue
//    window. Wave-private, read-only data, full unroll (static indices) —
//    zero protocol interaction. +16 VGPR.
// ---------------------------------------------------------------------------
__global__ __launch_bounds__(256, 1) void onlstm_persist(
    const short* __restrict__ xs, const short* __restrict__ Wsw,
    short* __restrict__ hs, float* __restrict__ cs,
    const float* __restrict__ bsum, void* __restrict__ out,
    const int* __restrict__ meta, int* __restrict__ ctr,
    int b_lo, int b_hi)
{
  __shared__ short Wl[NKB * 4 * 512];          // 128 KiB: frags f0..3
  __shared__ __align__(16) short Ht[NMB][32][40];  // 10 KiB: per-wave hy transpose

  const int tid  = threadIdx.x;
  const int lane = tid & 63;
  const int w    = tid >> 6;            // wave = mblock

  // XCD-grouped: group (rb,d) siblings (s=0..7) share lin%8 -> same XCD.
  const int lin = blockIdx.x;
  const int rb  = (lin & 7) + 8 * ((lin >> 3) >> 4);
  const int p   = (lin >> 3) & 15;
  const int d   = p >> 3;
  const int s   = p & 7;

  const int col   = lane & 31;
  const int khalf = lane >> 5;
  const int isf   = meta[0];

  const short* wsrc = Wsw + ((size_t)(d * NSL + s) * NKB) * (NF * 512);

  // ---- one-time: stage f0..3 frags into LDS (coalesced 16B/lane) ----
  for (int i = tid; i < NKB * 4 * 64; i += 256) {
    const int kb = i >> 8, rem = i & 255, f = rem >> 6, l = rem & 63;
    *(short8*)&Wl[((kb * 4 + f) << 9) + (l << 3)] =
        *(const short8*)(wsrc + ((kb * 5 + f) << 9) + (l << 3));
  }
  __syncthreads();

  // bias preloads (L1/L2 hits)
  float bg[4];
  #pragma unroll
  for (int f = 0; f < 4; ++f) bg[f] = bsum[16 + f * H_ + s * 32 + col];
  const float c0b = (col < 16) ? bsum[col] : 0.f;

  // epilogue addressing for e = s*32+col
  const int e = s * 32 + col;

  int* gctr = ctr + (size_t)(d * NRB + rb) * CTRSTRIDE;  // private cacheline
  const short* w4p = wsrc + 4 * 512 + lane * 8;   // f4 frag, stride 5*512/chunk

  float* csP = cs + (((size_t)(d * NSL + s) * NRB + rb) * NMB + w) * 1024 + lane;

  f32x16 creg;                                    // c carry: registers
  if (b_lo > 0) {
    #pragma unroll
    for (int r = 0; r < 16; ++r) creg[r] = csP[r * 64];
  } else {
    #pragma unroll
    for (int r = 0; r < 16; ++r) creg[r] = 0.f;
  }

  // prologue: synchronously prefetch step b_lo's xs chunks into registers
  short8 xn[16];
  {
    const short* aPtr = xs + (((size_t)b_lo * NRB + rb) * 16 * NMB + w) * 512 + lane * 8;
    #pragma unroll
    for (int kb = 0; kb < 16; ++kb)
      xn[kb] = *(const short8*)(aPtr + (size_t)kb * 2048);
  }

  for (int b = b_lo; b < b_hi; ++b) {
    const int len_s  = meta[8 + b];
    const int base_s = meta[40 + b];

    f32x16 acc[NF];
    #pragma unroll
    for (int f = 0; f < NF; ++f)
      #pragma unroll
      for (int r = 0; r < 16; ++r) acc[f][r] = 0.f;

    // ---- xs half (K chunks 0..15): A from registers (cross-step prefetch
    // into the same regs); Wl frags DOUBLE-BUFFERED in regs (kb+1's ds_reads
    // issued before kb's MFMAs); f4 pipelined 3-deep from global. ----
    {
      const short* aNext = xs + (((size_t)(b + 1) * NRB + rb) * 16 * NMB + w) * 512 + lane * 8;
      const bool pf = (b + 1 < b_hi);
      const short* w4q = w4p;
      short8 q0 = *(const short8*)(w4q);
      short8 q1 = *(const short8*)(w4q + 2560);
      short8 q2 = *(const short8*)(w4q + 5120);
      short8 wf[2][4];
      #pragma unroll
      for (int f = 0; f < 4; ++f)
        wf[0][f] = *(const short8*)&Wl[((0 * 4 + f) << 9) + (lane << 3)];
      #pragma unroll
      for (int kb = 0; kb < 16; ++kb) {
        const int cur = kb & 1;            // static after full unroll
        if (kb + 1 < 16) {
          #pragma unroll
          for (int f = 0; f < 4; ++f)
            wf[cur ^ 1][f] = *(const short8*)&Wl[(((kb + 1) * 4 + f) << 9) + (lane << 3)];
        }
        const short8 af = xn[kb];
        if (pf) xn[kb] = *(const short8*)(aNext + (size_t)kb * 2048);  // next-step prefetch
        const short8 b4 = q0;
        q0 = q1; q1 = q2;
        if (kb < 13) q2 = *(const short8*)(w4q + (kb + 3) * 2560);
        #pragma unroll
        for (int f = 0; f < 4; ++f)
          acc[f] = __builtin_amdgcn_mfma_f32_32x32x16_bf16(af, wf[cur][f], acc[f], 0, 0, 0);
        acc[4] = __builtin_amdgcn_mfma_f32_32x32x16_bf16(af, b4, acc[4], 0, 0, 0);
      }
    }

    // ---- wait: tid0 polls (8 sibling blocks signaled step b-1), then
    // __syncthreads releases the block (proven read side). ----
    if (b) {
      if (tid == 0) {
        ull t0 = __builtin_amdgcn_s_memrealtime();
        while (__hip_atomic_load(gctr, __ATOMIC_RELAXED,
                                 __HIP_MEMORY_SCOPE_AGENT) < 8 * b) {
          __builtin_amdgcn_s_sleep(1);
          if (__builtin_amdgcn_s_memrealtime() - t0 > 40000000ull) break; // no hang
        }
      }
      __syncthreads();

      // prefetch all 16 h-chunks (parity (b&1)^1) via coherent 8B atomic loads
      ull hfA[16], hfB[16];
      {
        const short* hbase = hs + (((size_t)(((b & 1) ^ 1) * 2 + d) * NRB + rb) * 16 * NMB + w) * 512;
        #pragma unroll
        for (int kb = 0; kb < 16; ++kb) {
          const ull* hp = (const ull*)(hbase + (size_t)kb * NMB * 512) + lane * 2;
          hfA[kb] = __hip_atomic_load(hp,     __ATOMIC_RELAXED, __HIP_MEMORY_SCOPE_AGENT);
          hfB[kb] = __hip_atomic_load(hp + 1, __ATOMIC_RELAXED, __HIP_MEMORY_SCOPE_AGENT);
        }
      }

      // hs half (K chunks 16..31): A from prefetched regs, Wl frags
      // double-buffered, f4 pipelined.
      const short* w4q = w4p + 16 * 2560;
      short8 q0 = *(const short8*)(w4q);
      short8 q1 = *(const short8*)(w4q + 2560);
      short8 q2 = *(const short8*)(w4q + 5120);
      short8 wf[2][4];
      #pragma unroll
      for (int f = 0; f < 4; ++f)
        wf[0][f] = *(const short8*)&Wl[(((16 * 4) + f) << 9) + (lane << 3)];
      #pragma unroll
      for (int kb = 0; kb < 16; ++kb) {
        const int cur = kb & 1;
        if (kb + 1 < 16) {
          #pragma unroll
          for (int f = 0; f < 4; ++f)
            wf[cur ^ 1][f] = *(const short8*)&Wl[(((16 + kb + 1) * 4 + f) << 9) + (lane << 3)];
        }
        union { ull u[2]; short8 v; } af;
        af.u[0] = hfA[kb]; af.u[1] = hfB[kb];
        const short8 b4 = q0;
        q0 = q1; q1 = q2;
        if (kb < 13) q2 = *(const short8*)(w4q + (kb + 3) * 2560);
        #pragma unroll
        for (int f = 0; f < 4; ++f)
          acc[f] = __builtin_amdgcn_mfma_f32_32x32x16_bf16(af.v, wf[cur][f], acc[f], 0, 0, 0);
        acc[4] = __builtin_amdgcn_mfma_f32_32x32x16_bf16(af.v, b4, acc[4], 0, 0, 0);
      }
    }
    // b==0: h is zero, hs half contributes nothing -> skipped entirely.

    // ---- epilogue ----
    // C layout: col = lane&31, row = (r&3) + 8*(r>>2) + 4*(lane>>5).
    // Stage-batched shuffle trees (16 parallel chains).
    f32x16 gv, mx, Sv, Pv;
    #pragma unroll
    for (int r = 0; r < 16; ++r) gv[r] = acc[4][r] + c0b;  // cols>=16: exactly 0
    #pragma unroll
    for (int r = 0; r < 16; ++r) mx[r] = gv[r];
    #pragma unroll
    for (int r = 0; r < 16; ++r) { float t = __shfl_xor(mx[r], 1); mx[r] = fmaxf(mx[r], t); }
    #pragma unroll
    for (int r = 0; r < 16; ++r) { float t = __shfl_xor(mx[r], 2); mx[r] = fmaxf(mx[r], t); }
    #pragma unroll
    for (int r = 0; r < 16; ++r) { float t = __shfl_xor(mx[r], 4); mx[r] = fmaxf(mx[r], t); }
    #pragma unroll
    for (int r = 0; r < 16; ++r) gv[r] = __expf(gv[r] - mx[r]);   // gv := ex
    const bool pin = (lane & 7) <= s;
    #pragma unroll
    for (int r = 0; r < 16; ++r) { Sv[r] = gv[r]; Pv[r] = pin ? gv[r] : 0.f; }
    #pragma unroll
    for (int r = 0; r < 16; ++r) { Sv[r] += __shfl_xor(Sv[r], 1); Pv[r] += __shfl_xor(Pv[r], 1); }
    #pragma unroll
    for (int r = 0; r < 16; ++r) { Sv[r] += __shfl_xor(Sv[r], 2); Pv[r] += __shfl_xor(Pv[r], 2); }
    #pragma unroll
    for (int r = 0; r < 16; ++r) { Sv[r] += __shfl_xor(Sv[r], 4); Pv[r] += __shfl_xor(Pv[r], 4); }
    #pragma unroll
    for (int r = 0; r < 16; ++r) Pv[r] = __fdividef(Pv[r], Sv[r]);  // Pv := ratio
    f32x16 cinv, cfgv;
    #pragma unroll
    for (int r = 0; r < 16; ++r) cinv[r] = 1.f - __shfl(Pv[r], khalf * 32);
    #pragma unroll
    for (int r = 0; r < 16; ++r) cfgv[r] = __shfl(Pv[r], khalf * 32 + 8);

    #pragma unroll
    for (int r = 0; r < 16; ++r) {
      const int row = (r & 3) + 8 * (r >> 2) + 4 * khalf;
      const float cin = cinv[r];
      const float cfg = cfgv[r];
      const float og = sigmoidf_(acc[0][r] + bg[0]);
      const float cg = tanh_   (acc[1][r] + bg[1]);
      const float ig = sigmoidf_(acc[2][r] + bg[2]);
      const float fg = sigmoidf_(acc[3][r] + bg[3]);
      const float ov = cfg * cin;
      const float f2 = fg * ov + (cfg - ov);
      const float i2 = ig * ov + (cin - ov);
      const float cy = f2 * creg[r] + i2 * cg;
      creg[r] = cy;
      const float hy = og * tanh_(cy);
      Ht[w][row][col] = f2bs(hy);         // wave-private transpose tile
      const int t = rb * 128 + w * 32 + row;
      if (t < len_s) {
        const size_t o = (size_t)(base_s + t) * (2 * H_) + (size_t)d * H_ + e;
        if (isf) ((float*)out)[o] = hy;
        else     ((bf16*)out)[o]  = __float2bfloat16(hy);
      }
    }

    // ---- hy -> A-frag image via coherent 8B atomic stores (4/lane) ----
    {
      const int m  = lane & 31;
      const int k8 = lane >> 5;
      short* hbase = hs + (((size_t)((b & 1) * 2 + d) * NRB + rb) * 16 * NMB + w) * 512;
      #pragma unroll
      for (int c = 0; c < 2; ++c) {
        ull lo = *(const ull*)&Ht[w][m][c * 16 + k8 * 8];
        ull hi = *(const ull*)&Ht[w][m][c * 16 + k8 * 8 + 4];
        ull* q = (ull*)(hbase + (size_t)(2 * s + c) * NMB * 512) + lane * 2;
        __hip_atomic_store(q,     lo, __ATOMIC_RELAXED, __HIP_MEMORY_SCOPE_AGENT);
        __hip_atomic_store(q + 1, hi, __ATOMIC_RELAXED, __HIP_MEMORY_SCOPE_AGENT);
      }
    }

    // ---- arrive: barrier drains all stores (vmcnt(0) before s_barrier),
    // then one RELAXED add signals (proven write side). ----
    __syncthreads();
    if (tid == 0)
      __hip_atomic_fetch_add(gctr, 1, __ATOMIC_RELAXED, __HIP_MEMORY_SCOPE_AGENT);
  }

  if (b_hi < B_) {                 // per-step fallback mode: spill c carry
    #pragma unroll
    for (int r = 0; r < 16; ++r) csP[r * 64] = creg[r];
  }
}

// ---------------------------------------------------------------------------
extern "C" void kernel_launch(void* const* d_in, const int* in_sizes, int n_in,
                              void* d_out, int out_size, void* d_ws, size_t ws_size,
                              hipStream_t stream)
{
  const void* x    = d_in[0];
  const int*  sl   = (const int*)d_in[1];
  const void* W_ih = d_in[2];
  const void* b_ih = d_in[3];
  const void* W_hh = d_in[4];
  const void* b_hh = d_in[5];

  char* ws = (char*)d_ws;
  size_t off = 0;
  auto alloc = [&](size_t bytes) {
    void* p = ws + off;
    off = (off + bytes + 255) & ~(size_t)255;
    return p;
  };
  int*   meta = (int*)  alloc(128 * sizeof(int));
  short* xs   = (short*)alloc((size_t)B_ * T_ * D_ * sizeof(short));            // 32 MB
  short* Wsw  = (short*)alloc((size_t)2 * NSL * NKB * NF * 512 * sizeof(short)); // 2.6 MB
  short* hs   = (short*)alloc((size_t)2 * 2 * T_ * H_ * sizeof(short));         // 4 MB [parity][dir]
  float* bsum = (float*)alloc((size_t)G_ * sizeof(float));
  int*   ctr  = (int*)  alloc((size_t)32 * CTRSTRIDE * sizeof(int));            // padded: 1 line/group
  float* cs   = (float*)alloc((size_t)2 * NSL * NRB * NMB * 1024 * sizeof(float)); // 4 MB (fallback only)
  const bool have_cs = (off <= ws_size);

  hipMemsetAsync(hs, 0, (size_t)2 * 2 * T_ * H_ * sizeof(short), stream);
  hipMemsetAsync(ctr, 0, (size_t)32 * CTRSTRIDE * sizeof(int), stream);

  detect_prep<<<1, 256, 0, stream>>>((const unsigned short*)x, sl, meta);
  build_bsum<<<(G_ + 255) / 256, 256, 0, stream>>>(b_ih, b_hh, bsum, meta);
  build_xs<<<(int)(((size_t)B_ * T_ * D_ / 8 + 255) / 256), 256, 0, stream>>>(x, (bf16*)xs, meta);
  build_wsw<<<(2 * NSL * NKB * NF * 64 + 255) / 256, 256, 0, stream>>>(W_ih, W_hh, (bf16*)Wsw, meta);

  // Preferred: cooperative persistent launch (co-residency guaranteed).
  int b_lo = 0, b_hi = B_;
  void* args[] = {(void*)&xs, (void*)&Wsw, (void*)&hs, (void*)&cs, (void*)&bsum,
                  (void*)&d_out, (void*)&meta, (void*)&ctr, (void*)&b_lo, (void*)&b_hi};
  hipError_t ce = hipLaunchCooperativeKernel((const void*)onlstm_persist,
                                             dim3(256), dim3(256), args, 0, stream);
  if (ce != hipSuccess) {
    (void)hipGetLastError();   // clear error state
    if (have_cs) {
      // Fallback: per-step launches; inter-step sync = kernel boundary.
      // Counter accumulates 8/group/launch, matching the 8*b thresholds.
      for (int b = 0; b < B_; ++b)
        onlstm_persist<<<dim3(256), dim3(256), 0, stream>>>(
            xs, Wsw, hs, cs, bsum, d_out, meta, ctr, b, b + 1);
    } else {
      // Last resort: regular persistent launch (structural residency + timeout).
      onlstm_persist<<<dim3(256), dim3(256), 0, stream>>>(
          xs, Wsw, hs, cs, bsum, d_out, meta, ctr, 0, B_);
    }
  }
}

// Round 13
// 599.708 us; speedup vs baseline: 2.6587x; 1.0022x over previous
//
#include <hip/hip_runtime.h>
#include <hip/hip_bf16.h>

// B=32, T=2048, D=256, H=256, CS=32, N=8, G=4H+2N=1040.
// Scan over BATCH axis (32 steps), carry (T,H). Backward dir = col-reversed W_ih.
#define B_  32
#define T_  2048
#define D_  256
#define H_  256
#define G_  1040

#define NSL 8      // e-slices of width 32 (== CS; slice s == chunk n)
#define NRB 16     // row-blocks of 128 rows
#define NMB 4      // mblocks (1 per wave) of 32 rows
#define NKB 32     // K16 chunks over KK=512
#define NF  5      // B col-frags: og,cg,ig,fg (32 cols) + [cols 0..15 | zeros]
#define CTRSTRIDE 64   // ints per group counter slot (256 B)

#define NBXS  8192   // build_xs blocks (B*T*D/8/256)
#define NBWSW 640    // build_wsw blocks (163840/256)

using bf16   = __hip_bfloat16;
using short8 = __attribute__((ext_vector_type(8))) short;
using f32x16 = __attribute__((ext_vector_type(16))) float;
using ull    = unsigned long long;

__device__ inline float sigmoidf_(float v) {
  return __fdividef(1.f, 1.f + __expf(-v));
}
__device__ inline float tanh_(float v) {
  v = fminf(fmaxf(v, -15.f), 15.f);
  float e = __expf(2.f * v);
  return __fdividef(e - 1.f, e + 1.f);
}
__device__ inline float bf2f(unsigned short u) {
  union { unsigned int i; float f; } c; c.i = ((unsigned int)u) << 16; return c.f;
}
__device__ inline float ldF(const void* p, size_t i, int isf) {
  return isf ? ((const float*)p)[i] : bf2f(((const unsigned short*)p)[i]);
}
__device__ inline short f2bs(float v) {
  bf16 h = __float2bfloat16(v);
  return *(short*)&h;
}

// ---------------------------------------------------------------------------
// Fused prep: ONE dispatch replaces detect_prep + build_bsum + build_xs +
// build_wsw (they serialized on the stream through the meta dependency).
// Every block recomputes the fp32-detection inline (2KB, L2-hot, parallel)
// so no block reads meta. Block 0 writes meta + bsum; blocks [1,1+NBXS) do
// the xs A-frag image; the rest do the Wsw B-frag image.
// ---------------------------------------------------------------------------
__global__ __launch_bounds__(256) void prep_all(
    const void* __restrict__ x, const int* __restrict__ sli,
    const void* __restrict__ W_ih, const void* __restrict__ b_ih,
    const void* __restrict__ W_hh, const void* __restrict__ b_hh,
    int* __restrict__ meta, float* __restrict__ bsum,
    bf16* __restrict__ xs, bf16* __restrict__ Wsw)
{
  const int tid = threadIdx.x;

  // ---- inline fp32 detection (identical semantics to detect_prep) ----
  __shared__ int s_bad;
  if (tid == 0) s_bad = 0;
  __syncthreads();
  {
    const unsigned short* xh = (const unsigned short*)x;
    int bad = 0;
    #pragma unroll
    for (int j = 0; j < 4; ++j) {
      float f = bf2f(xh[tid * 4 + j]);
      if (!(fabsf(f) < 100.f)) bad = 1;
    }
    if (bad) atomicOr(&s_bad, 1);
  }
  __syncthreads();
  const int isf = s_bad;

  const int blk = blockIdx.x;

  if (blk == 0) {
    // meta: [0]=is_fp32, [8+b]=seq_len[b], [40+b]=row base[b]
    if (tid == 0) {
      meta[0] = isf;
      bool is64 = true;
      for (int i = 1; i < 32; i += 2) if (sli[i] != 0) is64 = false;
      int base = 0;
      for (int b = 0; b < B_; ++b) {
        int v = is64 ? sli[2 * b] : sli[b];
        meta[8 + b]  = v;
        meta[40 + b] = base;
        base += v;
      }
    }
    for (int i = tid; i < G_; i += 256)
      bsum[i] = ldF(b_ih, i, isf) + ldF(b_hh, i, isf);
    return;
  }

  if (blk < 1 + NBXS) {
    // xs[b][rb(16)][kbx(16)][mb(4)][lane(64)][8]: A-frag image.
    // Vectorized: bf16 = one 16B copy; fp32 = 8 mergeable loads.
    const size_t idx = (size_t)(blk - 1) * 256 + tid;   // over B*T*D/8
    const int b  = (int)(idx >> 16);     // T*D/8 = 65536 per batch
    const int r  = (int)(idx & 65535);
    const int t  = r >> 5;               // 0..2047
    const int kc = r & 31;               // 8-elem k-chunk
    const size_t src = ((size_t)b * T_ + t) * D_ + kc * 8;
    short8 v;
    if (!isf) {
      v = *(const short8*)((const unsigned short*)x + src);
    } else {
      const float* xf = (const float*)x + src;
      #pragma unroll
      for (int j = 0; j < 8; ++j) v[j] = f2bs(xf[j]);
    }
    const int rb = t >> 7, mb = (t >> 5) & 3, trow = t & 31;
    const int kbx = kc >> 1, k8 = kc & 1;
    const size_t off = ((((size_t)b * 16 + rb) * 16 + kbx) * 4 + mb) * 64
                       + (k8 * 32 + trow);
    *(short8*)(xs + off * 8) = v;
    return;
  }

  // Wsw[d][s][kb(32)][f(5)][lane(64)][8]: B-frag image.
  {
    const int idx = (blk - 1 - NBXS) * 256 + tid;   // over 163840
    const int lane = idx & 63;
    const int f    = (idx >> 6) % NF;
    const int kb   = (idx / (64 * NF)) % NKB;
    const int sl   = (idx / (64 * NF * NKB)) % NSL;
    const int d    = idx / (64 * NF * NKB * NSL);
    const int n    = lane & 31;
    const int k0   = kb * 16 + (lane >> 5) * 8;
    const int g = (f < 4) ? (16 + f * H_ + sl * 32 + n) : ((n < 16) ? n : -1);
    short8 v;
    #pragma unroll
    for (int j = 0; j < 8; ++j) {
      float val = 0.f;
      const int k = k0 + j;
      if (g >= 0)
        val = (k < D_) ? ldF(W_ih, (size_t)g * D_ + (d ? (D_ - 1 - k) : k), isf)
                       : ldF(W_hh, (size_t)g * H_ + (k - D_), isf);
      v[j] = f2bs(val);
    }
    *(short8*)(Wsw + (size_t)idx * 8) = v;
  }
}

// ---------------------------------------------------------------------------
// Persistent fused recurrence. Round-13 = round-12 (best passing, 485us)
// byte-identical in sync structure + GEMMs; one free guard added:
//  - last step (b+1 >= B_) skips Ht writes + hy->hs atomic stores — that h
//    is never read, and skipping removes its store drain from the final
//    barrier. (Fallback audit: launch b reads >=8b, fed by launches 0..b-1;
//    launch 31's skipped stores are never waited on.)
// ---------------------------------------------------------------------------
__global__ __launch_bounds__(256, 1) void onlstm_persist(
    const short* __restrict__ xs, const short* __restrict__ Wsw,
    short* __restrict__ hs, float* __restrict__ cs,
    const float* __restrict__ bsum, void* __restrict__ out,
    const int* __restrict__ meta, int* __restrict__ ctr,
    int b_lo, int b_hi)
{
  __shared__ short Wl[NKB * 4 * 512];          // 128 KiB: frags f0..3
  __shared__ __align__(16) short Ht[NMB][32][40];  // 10 KiB: per-wave hy transpose

  const int tid  = threadIdx.x;
  const int lane = tid & 63;
  const int w    = tid >> 6;            // wave = mblock

  // XCD-grouped: group (rb,d) siblings (s=0..7) share lin%8 -> same XCD.
  const int lin = blockIdx.x;
  const int rb  = (lin & 7) + 8 * ((lin >> 3) >> 4);
  const int p   = (lin >> 3) & 15;
  const int d   = p >> 3;
  const int s   = p & 7;

  const int col   = lane & 31;
  const int khalf = lane >> 5;
  const int isf   = meta[0];

  const short* wsrc = Wsw + ((size_t)(d * NSL + s) * NKB) * (NF * 512);

  // ---- one-time: stage f0..3 frags into LDS (coalesced 16B/lane) ----
  for (int i = tid; i < NKB * 4 * 64; i += 256) {
    const int kb = i >> 8, rem = i & 255, f = rem >> 6, l = rem & 63;
    *(short8*)&Wl[((kb * 4 + f) << 9) + (l << 3)] =
        *(const short8*)(wsrc + ((kb * 5 + f) << 9) + (l << 3));
  }
  __syncthreads();

  // bias preloads (L1/L2 hits)
  float bg[4];
  #pragma unroll
  for (int f = 0; f < 4; ++f) bg[f] = bsum[16 + f * H_ + s * 32 + col];
  const float c0b = (col < 16) ? bsum[col] : 0.f;

  // epilogue addressing for e = s*32+col
  const int e = s * 32 + col;

  int* gctr = ctr + (size_t)(d * NRB + rb) * CTRSTRIDE;  // private cacheline
  const short* w4p = wsrc + 4 * 512 + lane * 8;   // f4 frag, stride 5*512/chunk

  float* csP = cs + (((size_t)(d * NSL + s) * NRB + rb) * NMB + w) * 1024 + lane;

  f32x16 creg;                                    // c carry: registers
  if (b_lo > 0) {
    #pragma unroll
    for (int r = 0; r < 16; ++r) creg[r] = csP[r * 64];
  } else {
    #pragma unroll
    for (int r = 0; r < 16; ++r) creg[r] = 0.f;
  }

  // prologue: synchronously prefetch step b_lo's xs chunks into registers
  short8 xn[16];
  {
    const short* aPtr = xs + (((size_t)b_lo * NRB + rb) * 16 * NMB + w) * 512 + lane * 8;
    #pragma unroll
    for (int kb = 0; kb < 16; ++kb)
      xn[kb] = *(const short8*)(aPtr + (size_t)kb * 2048);
  }

  for (int b = b_lo; b < b_hi; ++b) {
    const int len_s  = meta[8 + b];
    const int base_s = meta[40 + b];
    const bool lastb = (b + 1 >= B_);

    f32x16 acc[NF];
    #pragma unroll
    for (int f = 0; f < NF; ++f)
      #pragma unroll
      for (int r = 0; r < 16; ++r) acc[f][r] = 0.f;

    // ---- xs half (K chunks 0..15): A from registers (cross-step prefetch
    // into the same regs); Wl frags DOUBLE-BUFFERED in regs (kb+1's ds_reads
    // issued before kb's MFMAs); f4 pipelined 3-deep from global. ----
    {
      const short* aNext = xs + (((size_t)(b + 1) * NRB + rb) * 16 * NMB + w) * 512 + lane * 8;
      const bool pf = (b + 1 < b_hi);
      const short* w4q = w4p;
      short8 q0 = *(const short8*)(w4q);
      short8 q1 = *(const short8*)(w4q + 2560);
      short8 q2 = *(const short8*)(w4q + 5120);
      short8 wf[2][4];
      #pragma unroll
      for (int f = 0; f < 4; ++f)
        wf[0][f] = *(const short8*)&Wl[((0 * 4 + f) << 9) + (lane << 3)];
      #pragma unroll
      for (int kb = 0; kb < 16; ++kb) {
        const int cur = kb & 1;            // static after full unroll
        if (kb + 1 < 16) {
          #pragma unroll
          for (int f = 0; f < 4; ++f)
            wf[cur ^ 1][f] = *(const short8*)&Wl[(((kb + 1) * 4 + f) << 9) + (lane << 3)];
        }
        const short8 af = xn[kb];
        if (pf) xn[kb] = *(const short8*)(aNext + (size_t)kb * 2048);  // next-step prefetch
        const short8 b4 = q0;
        q0 = q1; q1 = q2;
        if (kb < 13) q2 = *(const short8*)(w4q + (kb + 3) * 2560);
        #pragma unroll
        for (int f = 0; f < 4; ++f)
          acc[f] = __builtin_amdgcn_mfma_f32_32x32x16_bf16(af, wf[cur][f], acc[f], 0, 0, 0);
        acc[4] = __builtin_amdgcn_mfma_f32_32x32x16_bf16(af, b4, acc[4], 0, 0, 0);
      }
    }

    // ---- wait: tid0 polls (8 sibling blocks signaled step b-1), then
    // __syncthreads releases the block (proven read side). ----
    if (b) {
      if (tid == 0) {
        ull t0 = __builtin_amdgcn_s_memrealtime();
        while (__hip_atomic_load(gctr, __ATOMIC_RELAXED,
                                 __HIP_MEMORY_SCOPE_AGENT) < 8 * b) {
          __builtin_amdgcn_s_sleep(1);
          if (__builtin_amdgcn_s_memrealtime() - t0 > 40000000ull) break; // no hang
        }
      }
      __syncthreads();

      // prefetch all 16 h-chunks (parity (b&1)^1) via coherent 8B atomic loads
      ull hfA[16], hfB[16];
      {
        const short* hbase = hs + (((size_t)(((b & 1) ^ 1) * 2 + d) * NRB + rb) * 16 * NMB + w) * 512;
        #pragma unroll
        for (int kb = 0; kb < 16; ++kb) {
          const ull* hp = (const ull*)(hbase + (size_t)kb * NMB * 512) + lane * 2;
          hfA[kb] = __hip_atomic_load(hp,     __ATOMIC_RELAXED, __HIP_MEMORY_SCOPE_AGENT);
          hfB[kb] = __hip_atomic_load(hp + 1, __ATOMIC_RELAXED, __HIP_MEMORY_SCOPE_AGENT);
        }
      }

      // hs half (K chunks 16..31): A from prefetched regs, Wl frags
      // double-buffered, f4 pipelined.
      const short* w4q = w4p + 16 * 2560;
      short8 q0 = *(const short8*)(w4q);
      short8 q1 = *(const short8*)(w4q + 2560);
      short8 q2 = *(const short8*)(w4q + 5120);
      short8 wf[2][4];
      #pragma unroll
      for (int f = 0; f < 4; ++f)
        wf[0][f] = *(const short8*)&Wl[(((16 * 4) + f) << 9) + (lane << 3)];
      #pragma unroll
      for (int kb = 0; kb < 16; ++kb) {
        const int cur = kb & 1;
        if (kb + 1 < 16) {
          #pragma unroll
          for (int f = 0; f < 4; ++f)
            wf[cur ^ 1][f] = *(const short8*)&Wl[(((16 + kb + 1) * 4 + f) << 9) + (lane << 3)];
        }
        union { ull u[2]; short8 v; } af;
        af.u[0] = hfA[kb]; af.u[1] = hfB[kb];
        const short8 b4 = q0;
        q0 = q1; q1 = q2;
        if (kb < 13) q2 = *(const short8*)(w4q + (kb + 3) * 2560);
        #pragma unroll
        for (int f = 0; f < 4; ++f)
          acc[f] = __builtin_amdgcn_mfma_f32_32x32x16_bf16(af.v, wf[cur][f], acc[f], 0, 0, 0);
        acc[4] = __builtin_amdgcn_mfma_f32_32x32x16_bf16(af.v, b4, acc[4], 0, 0, 0);
      }
    }
    // b==0: h is zero, hs half contributes nothing -> skipped entirely.

    // ---- epilogue ----
    // C layout: col = lane&31, row = (r&3) + 8*(r>>2) + 4*(lane>>5).
    // Stage-batched shuffle trees (16 parallel chains).
    f32x16 gv, mx, Sv, Pv;
    #pragma unroll
    for (int r = 0; r < 16; ++r) gv[r] = acc[4][r] + c0b;  // cols>=16: exactly 0
    #pragma unroll
    for (int r = 0; r < 16; ++r) mx[r] = gv[r];
    #pragma unroll
    for (int r = 0; r < 16; ++r) { float t = __shfl_xor(mx[r], 1); mx[r] = fmaxf(mx[r], t); }
    #pragma unroll
    for (int r = 0; r < 16; ++r) { float t = __shfl_xor(mx[r], 2); mx[r] = fmaxf(mx[r], t); }
    #pragma unroll
    for (int r = 0; r < 16; ++r) { float t = __shfl_xor(mx[r], 4); mx[r] = fmaxf(mx[r], t); }
    #pragma unroll
    for (int r = 0; r < 16; ++r) gv[r] = __expf(gv[r] - mx[r]);   // gv := ex
    const bool pin = (lane & 7) <= s;
    #pragma unroll
    for (int r = 0; r < 16; ++r) { Sv[r] = gv[r]; Pv[r] = pin ? gv[r] : 0.f; }
    #pragma unroll
    for (int r = 0; r < 16; ++r) { Sv[r] += __shfl_xor(Sv[r], 1); Pv[r] += __shfl_xor(Pv[r], 1); }
    #pragma unroll
    for (int r = 0; r < 16; ++r) { Sv[r] += __shfl_xor(Sv[r], 2); Pv[r] += __shfl_xor(Pv[r], 2); }
    #pragma unroll
    for (int r = 0; r < 16; ++r) { Sv[r] += __shfl_xor(Sv[r], 4); Pv[r] += __shfl_xor(Pv[r], 4); }
    #pragma unroll
    for (int r = 0; r < 16; ++r) Pv[r] = __fdividef(Pv[r], Sv[r]);  // Pv := ratio
    f32x16 cinv, cfgv;
    #pragma unroll
    for (int r = 0; r < 16; ++r) cinv[r] = 1.f - __shfl(Pv[r], khalf * 32);
    #pragma unroll
    for (int r = 0; r < 16; ++r) cfgv[r] = __shfl(Pv[r], khalf * 32 + 8);

    #pragma unroll
    for (int r = 0; r < 16; ++r) {
      const int row = (r & 3) + 8 * (r >> 2) + 4 * khalf;
      const float cin = cinv[r];
      const float cfg = cfgv[r];
      const float og = sigmoidf_(acc[0][r] + bg[0]);
      const float cg = tanh_   (acc[1][r] + bg[1]);
      const float ig = sigmoidf_(acc[2][r] + bg[2]);
      const float fg = sigmoidf_(acc[3][r] + bg[3]);
      const float ov = cfg * cin;
      const float f2 = fg * ov + (cfg - ov);
      const float i2 = ig * ov + (cin - ov);
      const float cy = f2 * creg[r] + i2 * cg;
      creg[r] = cy;
      const float hy = og * tanh_(cy);
      if (!lastb) Ht[w][row][col] = f2bs(hy);   // wave-private transpose tile
      const int t = rb * 128 + w * 32 + row;
      if (t < len_s) {
        const size_t o = (size_t)(base_s + t) * (2 * H_) + (size_t)d * H_ + e;
        if (isf) ((float*)out)[o] = hy;
        else     ((bf16*)out)[o]  = __float2bfloat16(hy);
      }
    }

    // ---- hy -> A-frag image via coherent 8B atomic stores (4/lane);
    // skipped on the last step (never read). ----
    if (!lastb) {
      const int m  = lane & 31;
      const int k8 = lane >> 5;
      short* hbase = hs + (((size_t)((b & 1) * 2 + d) * NRB + rb) * 16 * NMB + w) * 512;
      #pragma unroll
      for (int c = 0; c < 2; ++c) {
        ull lo = *(const ull*)&Ht[w][m][c * 16 + k8 * 8];
        ull hi = *(const ull*)&Ht[w][m][c * 16 + k8 * 8 + 4];
        ull* q = (ull*)(hbase + (size_t)(2 * s + c) * NMB * 512) + lane * 2;
        __hip_atomic_store(q,     lo, __ATOMIC_RELAXED, __HIP_MEMORY_SCOPE_AGENT);
        __hip_atomic_store(q + 1, hi, __ATOMIC_RELAXED, __HIP_MEMORY_SCOPE_AGENT);
      }
    }

    // ---- arrive: barrier drains all stores (vmcnt(0) before s_barrier),
    // then one RELAXED add signals (proven write side). ----
    __syncthreads();
    if (tid == 0)
      __hip_atomic_fetch_add(gctr, 1, __ATOMIC_RELAXED, __HIP_MEMORY_SCOPE_AGENT);
  }

  if (b_hi < B_) {                 // per-step fallback mode: spill c carry
    #pragma unroll
    for (int r = 0; r < 16; ++r) csP[r * 64] = creg[r];
  }
}

// ---------------------------------------------------------------------------
extern "C" void kernel_launch(void* const* d_in, const int* in_sizes, int n_in,
                              void* d_out, int out_size, void* d_ws, size_t ws_size,
                              hipStream_t stream)
{
  const void* x    = d_in[0];
  const int*  sl   = (const int*)d_in[1];
  const void* W_ih = d_in[2];
  const void* b_ih = d_in[3];
  const void* W_hh = d_in[4];
  const void* b_hh = d_in[5];

  char* ws = (char*)d_ws;
  size_t off = 0;
  auto alloc = [&](size_t bytes) {
    void* p = ws + off;
    off = (off + bytes + 255) & ~(size_t)255;
    return p;
  };
  int*   meta = (int*)  alloc(128 * sizeof(int));
  short* xs   = (short*)alloc((size_t)B_ * T_ * D_ * sizeof(short));            // 32 MB
  short* Wsw  = (short*)alloc((size_t)2 * NSL * NKB * NF * 512 * sizeof(short)); // 2.6 MB
  short* hs   = (short*)alloc((size_t)2 * 2 * T_ * H_ * sizeof(short));         // 4 MB [parity][dir]
  float* bsum = (float*)alloc((size_t)G_ * sizeof(float));
  int*   ctr  = (int*)  alloc((size_t)32 * CTRSTRIDE * sizeof(int));            // padded: 1 line/group
  float* cs   = (float*)alloc((size_t)2 * NSL * NRB * NMB * 1024 * sizeof(float)); // 4 MB (fallback only)
  const bool have_cs = (off <= ws_size);

  hipMemsetAsync(hs, 0, (size_t)2 * 2 * T_ * H_ * sizeof(short), stream);
  hipMemsetAsync(ctr, 0, (size_t)32 * CTRSTRIDE * sizeof(int), stream);

  // ONE fused prep dispatch (was 4 serialized: detect, bsum, xs, wsw).
  prep_all<<<1 + NBXS + NBWSW, 256, 0, stream>>>(
      x, sl, W_ih, b_ih, W_hh, b_hh, meta, bsum, (bf16*)xs, (bf16*)Wsw);

  // Preferred: cooperative persistent launch (co-residency guaranteed).
  int b_lo = 0, b_hi = B_;
  void* args[] = {(void*)&xs, (void*)&Wsw, (void*)&hs, (void*)&cs, (void*)&bsum,
                  (void*)&d_out, (void*)&meta, (void*)&ctr, (void*)&b_lo, (void*)&b_hi};
  hipError_t ce = hipLaunchCooperativeKernel((const void*)onlstm_persist,
                                             dim3(256), dim3(256), args, 0, stream);
  if (ce != hipSuccess) {
    (void)hipGetLastError();   // clear error state
    if (have_cs) {
      // Fallback: per-step launches; inter-step sync = kernel boundary.
      // Counter accumulates 8/group/launch, matching the 8*b thresholds.
      for (int b = 0; b < B_; ++b)
        onlstm_persist<<<dim3(256), dim3(256), 0, stream>>>(
            xs, Wsw, hs, cs, bsum, d_out, meta, ctr, b, b + 1);
    } else {
      // Last resort: regular persistent launch (structural residency + timeout).
      onlstm_persist<<<dim3(256), dim3(256), 0, stream>>>(
          xs, Wsw, hs, cs, bsum, d_out, meta, ctr, 0, B_);
    }
  }
}